// Round 5
// baseline (2061.341 us; speedup 1.0000x reference)
//
#include <hip/hip_runtime.h>
#include <hip/hip_bf16.h>

typedef unsigned short u16;
typedef __attribute__((ext_vector_type(8))) short frag8;   // 8 bf16
typedef __attribute__((ext_vector_type(4))) float facc4;   // 4 f32

#define L_SEQ 2048
#define D_MODEL 2048
#define N_HEADS 16
#define HEAD_D 128
#define N_QKV 6144
#define D_INNER 8192

__device__ __forceinline__ u16 f2b(float f) {
    __hip_bfloat16 h = __float2bfloat16(f);
    return *reinterpret_cast<u16*>(&h);
}

__device__ __forceinline__ float b2f(u16 u) {
    __hip_bfloat16 h = *reinterpret_cast<__hip_bfloat16*>(&u);
    return __bfloat162float(h);
}

__device__ __forceinline__ void gload_lds16(const void* g, void* l) {
    __builtin_amdgcn_global_load_lds(
        (const __attribute__((address_space(1))) unsigned int*)g,
        (__attribute__((address_space(3))) unsigned int*)l, 16, 0, 0);
}

__device__ __forceinline__ float gelu_exact(float x) {
    return 0.5f * x * (1.0f + erff(x * 0.7071067811865475f));
}

// ---------------- elementwise f32 -> bf16 ----------------
__global__ void cvt_bf16_kernel(const float* __restrict__ in, u16* __restrict__ out, int n) {
    int i = blockIdx.x * blockDim.x + threadIdx.x;
    int stride = gridDim.x * blockDim.x;
    for (; i < n; i += stride) out[i] = f2b(in[i]);
}

// ---------------- transpose + convert: in f32 [R][C] -> out bf16 [C][R] ----------------
__global__ void tr_cvt_kernel(const float* __restrict__ in, u16* __restrict__ out, int R, int C) {
    __shared__ float t[32][33];
    int bx = blockIdx.x * 32;  // C dim
    int by = blockIdx.y * 32;  // R dim
    int tx = threadIdx.x, ty = threadIdx.y;
#pragma unroll
    for (int k = 0; k < 32; k += 8) t[ty + k][tx] = in[(size_t)(by + ty + k) * C + bx + tx];
    __syncthreads();
#pragma unroll
    for (int k = 0; k < 32; k += 8) out[(size_t)(bx + ty + k) * R + by + tx] = f2b(t[tx][ty + k]);
}

// ---------------- legacy 128x128 GEMM (proj) ----------------
__global__ __launch_bounds__(256) void gemm_bt(const u16* __restrict__ A, const u16* __restrict__ Bt,
                                               const float* __restrict__ bias, float* __restrict__ Cout,
                                               int M, int N, int K) {
    __shared__ u16 lA[128 * 64];
    __shared__ u16 lB[128 * 64];
    const int tid = threadIdx.x;
    const int lane = tid & 63, wid = tid >> 6;
    const int wr = wid >> 1, wc = wid & 1;
    const int l15 = lane & 15, g4 = lane >> 4;
    const int bm = blockIdx.y, bn = blockIdx.x;

    const int arow = tid >> 3;
    const int acol = (tid & 7) * 8;
    const size_t abase = (size_t)(bm * 128) * K + acol;
    const size_t bbase = (size_t)(bn * 128) * K + acol;

    facc4 acc[4][4] = {};

    for (int k0 = 0; k0 < K; k0 += 64) {
        if (k0) __syncthreads();
#pragma unroll
        for (int i = 0; i < 4; i++) {
            gload_lds16(A + abase + (size_t)(i * 32 + arow) * K + k0, &lA[i * 2048 + tid * 8]);
            gload_lds16(Bt + bbase + (size_t)(i * 32 + arow) * K + k0, &lB[i * 2048 + tid * 8]);
        }
        __syncthreads();
#pragma unroll
        for (int kk = 0; kk < 64; kk += 32) {
            frag8 af[4], bf[4];
#pragma unroll
            for (int m = 0; m < 4; m++)
                af[m] = *(const frag8*)&lA[(wr * 64 + m * 16 + l15) * 64 + kk + g4 * 8];
#pragma unroll
            for (int n = 0; n < 4; n++)
                bf[n] = *(const frag8*)&lB[(wc * 64 + n * 16 + l15) * 64 + kk + g4 * 8];
#pragma unroll
            for (int m = 0; m < 4; m++)
#pragma unroll
                for (int n = 0; n < 4; n++)
                    acc[m][n] = __builtin_amdgcn_mfma_f32_16x16x32_bf16(af[m], bf[n], acc[m][n], 0, 0, 0);
        }
    }

    const int row0 = bm * 128 + wr * 64 + g4 * 4;
    const int col0 = bn * 128 + wc * 64 + l15;
#pragma unroll
    for (int n = 0; n < 4; n++) {
        const int col = col0 + n * 16;
        const float bv = bias[col];
#pragma unroll
        for (int m = 0; m < 4; m++)
#pragma unroll
            for (int r = 0; r < 4; r++)
                Cout[(size_t)(row0 + m * 16 + r) * N + col] = acc[m][n][r] + bv;
    }
}

// ---------------- gemm256 v2: 256x256 tile, BK=32, ring-2 LDS (64 KiB -> 2 blocks/CU) ----------------
// C[M,N] = A[M,K](bf16) * Bt[N,K](bf16)^T.  8 waves (2M x 4N), per-wave 128x64 output.
// Swizzle (verified 0-conflict): 16B chunk ^= ((row>>1)&3)<<4, both-sides (pre-swizzled global src).
// EPI: 0 f32+bias, 1 bf16+bias, 2 gelu+bf16+bias, 3 f32 partial (plane ptr by blockIdx.z, no bias)
template <int EPI>
__global__ __launch_bounds__(512, 4) void gemm256(const u16* __restrict__ A, const u16* __restrict__ Bt,
                                                  const float* __restrict__ bias, void* __restrict__ Cout,
                                                  float* __restrict__ q0, float* __restrict__ q1,
                                                  float* __restrict__ q2, float* __restrict__ q3,
                                                  int M, int N, int K, int kseg, int nbn) {
    __shared__ u16 lds[2 * 16384];  // buf b: A at b*16384, B at b*16384+8192 (u16 units)
    const int tid = threadIdx.x;
    const int lane = tid & 63, wid = tid >> 6;
    const int wm = wid >> 2, wn = wid & 3;
    const int l15 = lane & 15, g4 = lane >> 4;

    // XCD-chunked block swizzle (grids have nwg % 8 == 0)
    const int nwg = gridDim.x;
    const int q8 = nwg >> 3;
    const int wg = (blockIdx.x & 7) * q8 + (blockIdx.x >> 3);
    const int bn = wg % nbn, bm = wg / nbn;
    const int kb = blockIdx.z * kseg;
    const int ksz = (blockIdx.z == gridDim.z - 1) ? (K - kb) : kseg;
    const int nt = ksz >> 5;

    // staging: thread covers rows (tid>>2, +128), 16B chunk (tid&3); source pre-swizzled
    const int rA = tid >> 2;
    const int swzT = ((tid >> 3) & 3) << 4;             // ((rA>>1)&3)<<4  (bytes)
    const int srcE = ((((tid & 3) << 4) ^ swzT) >> 1);  // source elem offset within 32-elem row
    const u16* Ab = A + (size_t)(bm * 256 + rA) * K + kb + srcE;
    const u16* Bb = Bt + (size_t)(bn * 256 + rA) * K + kb + srcE;
    const size_t rstride = (size_t)128 * K;

    // fragment read offsets (u16 units), swizzle applied
    int aoff[8], boff[4];
#pragma unroll
    for (int mf = 0; mf < 8; mf++) {
        const int rowl = wm * 128 + mf * 16 + l15;
        aoff[mf] = rowl * 32 + (((g4 * 16) ^ (((rowl >> 1) & 3) << 4)) >> 1);
    }
#pragma unroll
    for (int nf = 0; nf < 4; nf++) {
        const int rowl = wn * 64 + nf * 16 + l15;
        boff[nf] = rowl * 32 + (((g4 * 16) ^ (((rowl >> 1) & 3) << 4)) >> 1);
    }

    auto stage = [&](int tt) {
        u16* s = &lds[(tt & 1) * 16384];
        const u16* ga = Ab + (size_t)tt * 32;
        const u16* gb = Bb + (size_t)tt * 32;
        gload_lds16(ga, s + tid * 8);
        gload_lds16(ga + rstride, s + 4096 + tid * 8);
        gload_lds16(gb, s + 8192 + tid * 8);
        gload_lds16(gb + rstride, s + 12288 + tid * 8);
    };

    facc4 acc[8][4] = {};

    stage(0);
    asm volatile("s_waitcnt vmcnt(0)" ::: "memory");
    __builtin_amdgcn_s_barrier();
    __builtin_amdgcn_sched_barrier(0);

    for (int t = 0; t < nt; ++t) {
        const u16* sA = &lds[(t & 1) * 16384];
        const u16* sB = sA + 8192;
        if (t + 1 < nt) stage(t + 1);  // into other buf (consumed at t-1)
        frag8 af[8], bf[4];
#pragma unroll
        for (int i = 0; i < 4; i++) bf[i] = *(const frag8*)&sB[boff[i]];
#pragma unroll
        for (int i = 0; i < 8; i++) af[i] = *(const frag8*)&sA[aoff[i]];
        __builtin_amdgcn_s_setprio(1);
#pragma unroll
        for (int mf = 0; mf < 8; mf++)
#pragma unroll
            for (int nf = 0; nf < 4; nf++)
                acc[mf][nf] = __builtin_amdgcn_mfma_f32_16x16x32_bf16(af[mf], bf[nf], acc[mf][nf], 0, 0, 0);
        __builtin_amdgcn_s_setprio(0);
        if (t + 1 < nt) asm volatile("s_waitcnt vmcnt(0)" ::: "memory");
        __builtin_amdgcn_s_barrier();
        __builtin_amdgcn_sched_barrier(0);
    }

    // ---- epilogue ----
    const int row0 = bm * 256 + wm * 128 + g4 * 4;
    const int col0 = bn * 256 + wn * 64 + l15;
    float* fout;
    if (EPI == 3) {
        const int z = blockIdx.z;
        fout = (z == 0) ? q0 : (z == 1) ? q1 : (z == 2) ? q2 : q3;
    } else {
        fout = (float*)Cout;
    }
#pragma unroll
    for (int nf = 0; nf < 4; nf++) {
        const int col = col0 + nf * 16;
        const float bv = (EPI == 3) ? 0.0f : bias[col];
#pragma unroll
        for (int mf = 0; mf < 8; mf++) {
#pragma unroll
            for (int r = 0; r < 4; r++) {
                const int row = row0 + mf * 16 + r;
                float v = acc[mf][nf][r] + bv;
                if (EPI == 2) v = gelu_exact(v);
                if (EPI == 0 || EPI == 3)
                    fout[(size_t)row * N + col] = v;
                else
                    ((u16*)Cout)[(size_t)row * N + col] = f2b(v);
            }
        }
    }
}

// ---------------- flash attention: 4 waves/block, 64 q-rows/block, KVBLK=64 ----------------
__global__ __launch_bounds__(256) void attn_kernel(const u16* __restrict__ qkv, u16* __restrict__ out) {
    __shared__ u16 kT[64 * 128];
    __shared__ u16 vT[128 * 72];
    const int h = blockIdx.y;
    const int qb = (int)gridDim.x - 1 - (int)blockIdx.x;  // heavy blocks first
    const int tid = threadIdx.x;
    const int lane = tid & 63, w = tid >> 6;
    const int l15 = lane & 15, g4 = lane >> 4;
    const int q0 = qb * 64 + w * 16;
    const float scale = 0.022097086912079608f;  // 1/sqrt(2048)

    frag8 qf[4];
    {
        const u16* qrow = qkv + (size_t)(q0 + l15) * N_QKV + h * HEAD_D + g4 * 8;
#pragma unroll
        for (int c = 0; c < 4; c++) qf[c] = *(const frag8*)(qrow + c * 32);
    }

    float m_run = -1e30f, l_run = 0.0f;
    facc4 o[8] = {};

    const int src0 = ((g4 & 1) << 5) + l15;
    const int src1 = src0 + 16;
    const bool hi = (g4 & 2) != 0;

    const int nt = qb + 1;
    for (int t = 0; t < nt; ++t) {
        const int kbase = t * 64;
        if (t) __syncthreads();
        const u16* kg_ptr = qkv + (size_t)kbase * N_QKV + D_MODEL + h * HEAD_D;
        const u16* vg_ptr = kg_ptr + D_MODEL;
        uint4 vv[4];
#pragma unroll
        for (int i = 0; i < 4; ++i)
            vv[i] = *(const uint4*)(vg_ptr + (size_t)lane * N_QKV + w * 32 + i * 8);
#pragma unroll
        for (int p = 0; p < 4; ++p) {
            const int c = p * 256 + tid;
            const int row = c >> 4;
            const int colb = (c & 15) << 4;
            const int srcb = colb ^ ((row & 7) << 4);
            gload_lds16(kg_ptr + (size_t)row * N_QKV + (srcb >> 1), &kT[c * 8]);
        }
#pragma unroll
        for (int i = 0; i < 4; ++i) {
            const u16* pv = (const u16*)&vv[i];
#pragma unroll
            for (int e = 0; e < 8; ++e)
                vT[(w * 32 + i * 8 + e) * 72 + lane] = pv[e];
        }
        __syncthreads();

        const bool last = (t == nt - 1);

        float st[16];
        float mx = -1e30f;
#pragma unroll
        for (int ks = 0; ks < 4; ++ks) {
            const bool active = !last || (ks <= w);
            if (active) {
                facc4 s = {};
                const int kl = ks * 16 + l15;
#pragma unroll
                for (int c = 0; c < 4; ++c) {
                    const int colb = (g4 * 16 + c * 64) ^ ((kl & 7) << 4);
                    frag8 kf = *(const frag8*)&kT[kl * 128 + (colb >> 1)];
                    s = __builtin_amdgcn_mfma_f32_16x16x32_bf16(kf, qf[c], s, 0, 0, 0);
                }
#pragma unroll
                for (int r = 0; r < 4; ++r) {
                    float v = s[r] * scale;
                    if (last) {
                        const int key = kbase + ks * 16 + g4 * 4 + r;
                        if (key > q0 + l15) v = -1e30f;
                    }
                    st[ks * 4 + r] = v;
                    mx = fmaxf(mx, v);
                }
            } else {
#pragma unroll
                for (int r = 0; r < 4; ++r) st[ks * 4 + r] = -1e30f;
            }
        }

        mx = fmaxf(mx, __shfl_xor(mx, 16));
        mx = fmaxf(mx, __shfl_xor(mx, 32));
        const float m_new = fmaxf(m_run, mx);
        const float alpha = __expf(m_run - m_new);
        float ps = 0.0f;
        uint2 pb[4];
#pragma unroll
        for (int ks = 0; ks < 4; ++ks) {
            const float p0 = __expf(st[ks * 4 + 0] - m_new);
            const float p1 = __expf(st[ks * 4 + 1] - m_new);
            const float p2 = __expf(st[ks * 4 + 2] - m_new);
            const float p3 = __expf(st[ks * 4 + 3] - m_new);
            ps += (p0 + p1) + (p2 + p3);
            pb[ks].x = (unsigned)f2b(p0) | ((unsigned)f2b(p1) << 16);
            pb[ks].y = (unsigned)f2b(p2) | ((unsigned)f2b(p3) << 16);
        }
        ps += __shfl_xor(ps, 16);
        ps += __shfl_xor(ps, 32);
        l_run = l_run * alpha + ps;
        m_run = m_new;
#pragma unroll
        for (int c8 = 0; c8 < 8; ++c8)
#pragma unroll
            for (int r = 0; r < 4; ++r) o[c8][r] *= alpha;

#pragma unroll
        for (int kp = 0; kp < 2; ++kp) {
            const bool kp_active = !last || (kp == 0) || (w >= 2);
            if (kp_active) {
                const uint2 a = pb[2 * kp], b = pb[2 * kp + 1];
                const unsigned a0 = __shfl(a.x, src0), a1 = __shfl(a.y, src0);
                const unsigned a2 = __shfl(a.x, src1), a3 = __shfl(a.y, src1);
                const unsigned b0 = __shfl(b.x, src0), b1 = __shfl(b.y, src0);
                const unsigned b2 = __shfl(b.x, src1), b3 = __shfl(b.y, src1);
                union { unsigned u[4]; frag8 f; } pu;
                pu.u[0] = hi ? b0 : a0;
                pu.u[1] = hi ? b1 : a1;
                pu.u[2] = hi ? b2 : a2;
                pu.u[3] = hi ? b3 : a3;
                const frag8 pf = pu.f;
#pragma unroll
                for (int c8 = 0; c8 < 8; ++c8) {
                    frag8 vf = *(const frag8*)&vT[(c8 * 16 + l15) * 72 + kp * 32 + g4 * 8];
                    o[c8] = __builtin_amdgcn_mfma_f32_16x16x32_bf16(vf, pf, o[c8], 0, 0, 0);
                }
            }
        }
    }

    const float inv_l = 1.0f / l_run;
    u16* orow = out + (size_t)(q0 + l15) * D_MODEL + h * HEAD_D;
#pragma unroll
    for (int c8 = 0; c8 < 8; ++c8) {
        uint2 st2;
        st2.x = (unsigned)f2b(o[c8][0] * inv_l) | ((unsigned)f2b(o[c8][1] * inv_l) << 16);
        st2.y = (unsigned)f2b(o[c8][2] * inv_l) | ((unsigned)f2b(o[c8][3] * inv_l) << 16);
        *(uint2*)&orow[c8 * 16 + g4 * 4] = st2;
    }
}

// ---------------- residual + layernorm -> bf16 ----------------
__global__ __launch_bounds__(256) void ln_kernel(const float* __restrict__ a, const float* __restrict__ b,
                                                 const float* __restrict__ gamma, const float* __restrict__ beta,
                                                 u16* __restrict__ outb) {
    __shared__ float red[8];
    const int row = blockIdx.x;
    const int tid = threadIdx.x;
    const float* pa = a + (size_t)row * D_MODEL;
    const float* pb = b + (size_t)row * D_MODEL;
    float v[8];
    float s = 0.0f, s2 = 0.0f;
#pragma unroll
    for (int i = 0; i < 8; i++) {
        const int c = tid + i * 256;
        const float x = pa[c] + pb[c];
        v[i] = x;
        s += x;
        s2 += x * x;
    }
#pragma unroll
    for (int off = 32; off; off >>= 1) {
        s += __shfl_xor(s, off);
        s2 += __shfl_xor(s2, off);
    }
    if ((tid & 63) == 0) { red[(tid >> 6) * 2] = s; red[(tid >> 6) * 2 + 1] = s2; }
    __syncthreads();
    s = red[0] + red[2] + red[4] + red[6];
    s2 = red[1] + red[3] + red[5] + red[7];
    const float mean = s * (1.0f / D_MODEL);
    const float var = s2 * (1.0f / D_MODEL) - mean * mean;
    const float rstd = rsqrtf(var + 1e-5f);
#pragma unroll
    for (int i = 0; i < 8; i++) {
        const int c = tid + i * 256;
        outb[(size_t)row * D_MODEL + c] = f2b((v[i] - mean) * rstd * gamma[c] + beta[c]);
    }
}

// ---------------- bf16 residual + Σ split-K partials + bias + layernorm -> f32 ----------------
__global__ __launch_bounds__(256) void ln_part_kernel(const u16* __restrict__ hb,
                                                      const float* __restrict__ p0, const float* __restrict__ p1,
                                                      const float* __restrict__ p2, const float* __restrict__ p3,
                                                      int np, const float* __restrict__ bias,
                                                      const float* __restrict__ gamma, const float* __restrict__ beta,
                                                      float* __restrict__ outf) {
    __shared__ float red[8];
    const int row = blockIdx.x;
    const int tid = threadIdx.x;
    const size_t rb = (size_t)row * D_MODEL;
    float v[8];
    float s = 0.0f, s2 = 0.0f;
#pragma unroll
    for (int i = 0; i < 8; i++) {
        const int c = tid + i * 256;
        float x = b2f(hb[rb + c]) + bias[c] + p0[rb + c] + p1[rb + c];
        if (np > 2) x += p2[rb + c];
        if (np > 3) x += p3[rb + c];
        v[i] = x;
        s += x;
        s2 += x * x;
    }
#pragma unroll
    for (int off = 32; off; off >>= 1) {
        s += __shfl_xor(s, off);
        s2 += __shfl_xor(s2, off);
    }
    if ((tid & 63) == 0) { red[(tid >> 6) * 2] = s; red[(tid >> 6) * 2 + 1] = s2; }
    __syncthreads();
    s = red[0] + red[2] + red[4] + red[6];
    s2 = red[1] + red[3] + red[5] + red[7];
    const float mean = s * (1.0f / D_MODEL);
    const float var = s2 * (1.0f / D_MODEL) - mean * mean;
    const float rstd = rsqrtf(var + 1e-5f);
#pragma unroll
    for (int i = 0; i < 8; i++) {
        const int c = tid + i * 256;
        outf[rb + c] = (v[i] - mean) * rstd * gamma[c] + beta[c];
    }
}

extern "C" void kernel_launch(void* const* d_in, const int* in_sizes, int n_in,
                              void* d_out, int out_size, void* d_ws, size_t ws_size,
                              hipStream_t stream) {
    const float* x    = (const float*)d_in[0];
    const float* Wqkv = (const float*)d_in[1];
    const float* bqkv = (const float*)d_in[2];
    const float* Wo   = (const float*)d_in[3];
    const float* bo   = (const float*)d_in[4];
    const float* W1   = (const float*)d_in[5];
    const float* b1   = (const float*)d_in[6];
    const float* W2   = (const float*)d_in[7];
    const float* b2   = (const float*)d_in[8];
    const float* g1   = (const float*)d_in[9];
    const float* be1  = (const float*)d_in[10];
    const float* g2   = (const float*)d_in[11];
    const float* be2  = (const float*)d_in[12];

    char* ws = (char*)d_ws;
    const size_t MB = 1024 * 1024;
    // layout (stream-ordered reuse; peak 120 MB, 136 MB if available):
    u16*  xb     = (u16*)(ws + 0);          // [0,8)
    u16*  WqkvT  = (u16*)(ws + 8 * MB);     // [8,32)
    u16*  qkv    = (u16*)(ws + 32 * MB);    // [32,56)
    u16*  attn_o = (u16*)(ws + 56 * MB);    // [56,64)
    u16*  WoT    = (u16*)(ws + 8 * MB);     // [8,16)   reuses WqkvT (dead)
    float* proj  = (float*)(ws + 16 * MB);  // [16,32)
    u16*  hb     = (u16*)(ws + 0);          // [0,8)    reuses xb (dead)
    u16*  W1T    = (u16*)(ws + 8 * MB);     // [8,40)   reuses WoT+proj (dead)
    u16*  f1     = (u16*)(ws + 40 * MB);    // [40,72)
    u16*  W2T    = (u16*)(ws + 72 * MB);    // [72,104)
    float* part0 = (float*)(ws + 8 * MB);   // [8,24)   reuses W1T (dead)
    float* part1 = (float*)(ws + 24 * MB);  // [24,40)
    float* part2 = (float*)(ws + 104 * MB); // [104,120)
    float* part3 = (float*)(ws + 120 * MB); // [120,136) only if ws >= 136 MB

    const int np = (ws_size >= 136 * MB) ? 4 : 3;
    const int kseg = (np == 4) ? 2048 : 2688;  // last z-plane takes remainder (2048 / 2816)

    const dim3 b32(32, 8);

    // 1. x -> bf16
    cvt_bf16_kernel<<<2048, 256, 0, stream>>>(x, xb, L_SEQ * D_MODEL);
    // 2. Wqkv^T
    tr_cvt_kernel<<<dim3(N_QKV / 32, D_MODEL / 32), b32, 0, stream>>>(Wqkv, WqkvT, D_MODEL, N_QKV);
    // 3. qkv = x @ Wqkv + bqkv (bf16), grid 8x24 = 192
    gemm256<1><<<dim3(192, 1, 1), 512, 0, stream>>>(xb, WqkvT, bqkv, qkv, nullptr, nullptr, nullptr, nullptr,
                                                    L_SEQ, N_QKV, D_MODEL, D_MODEL, 24);
    // 4. attention
    attn_kernel<<<dim3(L_SEQ / 64, N_HEADS), 256, 0, stream>>>(qkv, attn_o);
    // 5. Wo^T
    tr_cvt_kernel<<<dim3(D_MODEL / 32, D_MODEL / 32), b32, 0, stream>>>(Wo, WoT, D_MODEL, D_MODEL);
    // 6. proj = attn @ Wo + bo (f32)
    gemm_bt<<<dim3(D_MODEL / 128, L_SEQ / 128), 256, 0, stream>>>(attn_o, WoT, bo, proj, L_SEQ, D_MODEL, D_MODEL);
    // 7. hb = bf16(LN(x + proj))
    ln_kernel<<<L_SEQ, 256, 0, stream>>>(x, proj, g1, be1, hb);
    // 8. W1^T
    tr_cvt_kernel<<<dim3(D_INNER / 32, D_MODEL / 32), b32, 0, stream>>>(W1, W1T, D_MODEL, D_INNER);
    // 9. f1 = gelu(hb @ W1 + b1) (bf16), grid 8x32 = 256
    gemm256<2><<<dim3(256, 1, 1), 512, 0, stream>>>(hb, W1T, b1, f1, nullptr, nullptr, nullptr, nullptr,
                                                    L_SEQ, D_INNER, D_MODEL, D_MODEL, 32);
    // 10. W2^T
    tr_cvt_kernel<<<dim3(D_MODEL / 32, D_INNER / 32), b32, 0, stream>>>(W2, W2T, D_INNER, D_MODEL);
    // 11. f2 partials = f1 @ W2 (split-K=np, f32 planes)
    gemm256<3><<<dim3(64, 1, np), 512, 0, stream>>>(f1, W2T, nullptr, nullptr, part0, part1, part2, part3,
                                                    L_SEQ, D_MODEL, D_INNER, kseg, 8);
    // 12. out = LN(hb + Σparts + b2)*g2+be2
    ln_part_kernel<<<L_SEQ, 256, 0, stream>>>(hb, part0, part1, part2, part3, np, b2, g2, be2, (float*)d_out);
}

// Round 6
// 483.245 us; speedup vs baseline: 4.2656x; 4.2656x over previous
//
#include <hip/hip_runtime.h>
#include <hip/hip_bf16.h>

typedef unsigned short u16;
typedef __attribute__((ext_vector_type(8))) short frag8;   // 8 bf16
typedef __attribute__((ext_vector_type(4))) float facc4;   // 4 f32

#define L_SEQ 2048
#define D_MODEL 2048
#define N_HEADS 16
#define HEAD_D 128
#define N_QKV 6144
#define D_INNER 8192

__device__ __forceinline__ u16 f2b(float f) {
    __hip_bfloat16 h = __float2bfloat16(f);
    return *reinterpret_cast<u16*>(&h);
}

__device__ __forceinline__ float b2f(u16 u) {
    __hip_bfloat16 h = *reinterpret_cast<__hip_bfloat16*>(&u);
    return __bfloat162float(h);
}

__device__ __forceinline__ void gload_lds16(const void* g, void* l) {
    __builtin_amdgcn_global_load_lds(
        (const __attribute__((address_space(1))) unsigned int*)g,
        (__attribute__((address_space(3))) unsigned int*)l, 16, 0, 0);
}

__device__ __forceinline__ float gelu_exact(float x) {
    return 0.5f * x * (1.0f + erff(x * 0.7071067811865475f));
}

// ---------------- elementwise f32 -> bf16 ----------------
__global__ void cvt_bf16_kernel(const float* __restrict__ in, u16* __restrict__ out, int n) {
    int i = blockIdx.x * blockDim.x + threadIdx.x;
    int stride = gridDim.x * blockDim.x;
    for (; i < n; i += stride) out[i] = f2b(in[i]);
}

// ---------------- transpose + convert: in f32 [R][C] -> out bf16 [C][R] ----------------
__global__ void tr_cvt_kernel(const float* __restrict__ in, u16* __restrict__ out, int R, int C) {
    __shared__ float t[32][33];
    int bx = blockIdx.x * 32;  // C dim
    int by = blockIdx.y * 32;  // R dim
    int tx = threadIdx.x, ty = threadIdx.y;
#pragma unroll
    for (int k = 0; k < 32; k += 8) t[ty + k][tx] = in[(size_t)(by + ty + k) * C + bx + tx];
    __syncthreads();
#pragma unroll
    for (int k = 0; k < 32; k += 8) out[(size_t)(bx + ty + k) * R + by + tx] = f2b(t[tx][ty + k]);
}

// ---------------- legacy 128x128 GEMM (proj) ----------------
__global__ __launch_bounds__(256) void gemm_bt(const u16* __restrict__ A, const u16* __restrict__ Bt,
                                               const float* __restrict__ bias, float* __restrict__ Cout,
                                               int M, int N, int K) {
    __shared__ u16 lA[128 * 64];
    __shared__ u16 lB[128 * 64];
    const int tid = threadIdx.x;
    const int lane = tid & 63, wid = tid >> 6;
    const int wr = wid >> 1, wc = wid & 1;
    const int l15 = lane & 15, g4 = lane >> 4;
    const int bm = blockIdx.y, bn = blockIdx.x;

    const int arow = tid >> 3;
    const int acol = (tid & 7) * 8;
    const size_t abase = (size_t)(bm * 128) * K + acol;
    const size_t bbase = (size_t)(bn * 128) * K + acol;

    facc4 acc[4][4] = {};

    for (int k0 = 0; k0 < K; k0 += 64) {
        if (k0) __syncthreads();
#pragma unroll
        for (int i = 0; i < 4; i++) {
            gload_lds16(A + abase + (size_t)(i * 32 + arow) * K + k0, &lA[i * 2048 + tid * 8]);
            gload_lds16(Bt + bbase + (size_t)(i * 32 + arow) * K + k0, &lB[i * 2048 + tid * 8]);
        }
        __syncthreads();
#pragma unroll
        for (int kk = 0; kk < 64; kk += 32) {
            frag8 af[4], bf[4];
#pragma unroll
            for (int m = 0; m < 4; m++)
                af[m] = *(const frag8*)&lA[(wr * 64 + m * 16 + l15) * 64 + kk + g4 * 8];
#pragma unroll
            for (int n = 0; n < 4; n++)
                bf[n] = *(const frag8*)&lB[(wc * 64 + n * 16 + l15) * 64 + kk + g4 * 8];
#pragma unroll
            for (int m = 0; m < 4; m++)
#pragma unroll
                for (int n = 0; n < 4; n++)
                    acc[m][n] = __builtin_amdgcn_mfma_f32_16x16x32_bf16(af[m], bf[n], acc[m][n], 0, 0, 0);
        }
    }

    const int row0 = bm * 128 + wr * 64 + g4 * 4;
    const int col0 = bn * 128 + wc * 64 + l15;
#pragma unroll
    for (int n = 0; n < 4; n++) {
        const int col = col0 + n * 16;
        const float bv = bias[col];
#pragma unroll
        for (int m = 0; m < 4; m++)
#pragma unroll
            for (int r = 0; r < 4; r++)
                Cout[(size_t)(row0 + m * 16 + r) * N + col] = acc[m][n][r] + bv;
    }
}

// ---------------- gemm256 v6: 256x256 tile, BK=32, ring-4 LDS (128 KiB), sub-phased reads ----------------
// Round-4-proven dataflow: stage-ahead-3, counted vmcnt(8), 2 barriers/tile, T2 swizzle (0 conflicts).
// v6 refinement (race-free: read-read reorder only): reads split into 4 sub-phases interleaved
// with 8-MFMA clusters instead of one 12-read burst before 32 MFMAs.
// EPI: 0 f32+bias, 1 bf16+bias, 2 gelu+bf16+bias, 3 f32 partial (plane by blockIdx.z, no bias)
template <int EPI>
__global__ __launch_bounds__(512, 2) void gemm256(const u16* __restrict__ A, const u16* __restrict__ Bt,
                                                  const float* __restrict__ bias, void* __restrict__ Cout,
                                                  float* __restrict__ q0, float* __restrict__ q1,
                                                  float* __restrict__ q2, float* __restrict__ q3,
                                                  int M, int N, int K, int kseg, int nbn) {
    __shared__ u16 lds[4 * 16384];  // stage s: A at s*16384, B at s*16384+8192 (u16 units)
    const int tid = threadIdx.x;
    const int lane = tid & 63, wid = tid >> 6;
    const int wm = wid >> 2, wn = wid & 3;
    const int l15 = lane & 15, g4 = lane >> 4;

    // XCD-chunked block swizzle (grids have nwg % 8 == 0)
    const int nwg = gridDim.x;
    const int q8 = nwg >> 3;
    const int wg = (blockIdx.x & 7) * q8 + (blockIdx.x >> 3);
    const int bn = wg % nbn, bm = wg / nbn;
    const int kb = blockIdx.z * kseg;
    const int ksz = (blockIdx.z == (int)gridDim.z - 1) ? (K - kb) : kseg;
    const int nt = ksz >> 5;

    // staging: thread covers rows (tid>>2, +128), 16B chunk (tid&3); source pre-swizzled
    const int rA = tid >> 2;
    const int swzT = ((tid >> 3) & 3) << 4;             // ((rA>>1)&3)<<4  (bytes)
    const int srcE = ((((tid & 3) << 4) ^ swzT) >> 1);  // source elem offset within 32-elem row
    const u16* Ab = A + (size_t)(bm * 256 + rA) * K + kb + srcE;
    const u16* Bb = Bt + (size_t)(bn * 256 + rA) * K + kb + srcE;
    const size_t rstride = (size_t)128 * K;

    // fragment read offsets (u16 units), swizzle applied
    int aoff[8], boff[4];
#pragma unroll
    for (int mf = 0; mf < 8; mf++) {
        const int rowl = wm * 128 + mf * 16 + l15;
        aoff[mf] = rowl * 32 + (((g4 * 16) ^ (((rowl >> 1) & 3) << 4)) >> 1);
    }
#pragma unroll
    for (int nf = 0; nf < 4; nf++) {
        const int rowl = wn * 64 + nf * 16 + l15;
        boff[nf] = rowl * 32 + (((g4 * 16) ^ (((rowl >> 1) & 3) << 4)) >> 1);
    }

    auto stageA = [&](int tt) {
        u16* sA = &lds[(tt & 3) * 16384];
        const u16* g = Ab + (size_t)tt * 32;
        gload_lds16(g, sA + tid * 8);
        gload_lds16(g + rstride, sA + 4096 + tid * 8);
    };
    auto stageB = [&](int tt) {
        u16* sB = &lds[(tt & 3) * 16384 + 8192];
        const u16* g = Bb + (size_t)tt * 32;
        gload_lds16(g, sB + tid * 8);
        gload_lds16(g + rstride, sB + 4096 + tid * 8);
    };

    facc4 acc[8][4] = {};

    // prologue: stage tiles 0,1,2; confirm tile 0 (8 newest stay in flight)
    stageA(0); stageB(0);
    stageA(1); stageB(1);
    stageA(2); stageB(2);
    asm volatile("s_waitcnt vmcnt(8)" ::: "memory");
    __builtin_amdgcn_s_barrier();
    __builtin_amdgcn_sched_barrier(0);

    for (int t = 0; t < nt; ++t) {
        const u16* sA = &lds[(t & 3) * 16384];
        const u16* sB = sA + 8192;
        // ---- s0: B frags + A 0,1 ----
        frag8 b0[4], ap[2];
#pragma unroll
        for (int i = 0; i < 4; i++) b0[i] = *(const frag8*)&sB[boff[i]];
        ap[0] = *(const frag8*)&sA[aoff[0]];
        ap[1] = *(const frag8*)&sA[aoff[1]];
        if (t + 3 < nt) stageA(t + 3);
        __builtin_amdgcn_s_setprio(1);
#pragma unroll
        for (int m = 0; m < 2; m++)
#pragma unroll
            for (int nf = 0; nf < 4; nf++)
                acc[m][nf] = __builtin_amdgcn_mfma_f32_16x16x32_bf16(ap[m], b0[nf], acc[m][nf], 0, 0, 0);
        __builtin_amdgcn_s_setprio(0);
        // ---- s1: A 2,3 ----
        ap[0] = *(const frag8*)&sA[aoff[2]];
        ap[1] = *(const frag8*)&sA[aoff[3]];
        __builtin_amdgcn_s_setprio(1);
#pragma unroll
        for (int m = 0; m < 2; m++)
#pragma unroll
            for (int nf = 0; nf < 4; nf++)
                acc[2 + m][nf] = __builtin_amdgcn_mfma_f32_16x16x32_bf16(ap[m], b0[nf], acc[2 + m][nf], 0, 0, 0);
        __builtin_amdgcn_s_setprio(0);
        __builtin_amdgcn_s_barrier();  // mid-tile barrier (round-4 topology)
        // ---- s2: A 4,5 ----
        ap[0] = *(const frag8*)&sA[aoff[4]];
        ap[1] = *(const frag8*)&sA[aoff[5]];
        if (t + 3 < nt) stageB(t + 3);
        __builtin_amdgcn_s_setprio(1);
#pragma unroll
        for (int m = 0; m < 2; m++)
#pragma unroll
            for (int nf = 0; nf < 4; nf++)
                acc[4 + m][nf] = __builtin_amdgcn_mfma_f32_16x16x32_bf16(ap[m], b0[nf], acc[4 + m][nf], 0, 0, 0);
        __builtin_amdgcn_s_setprio(0);
        // ---- s3: A 6,7 ----
        ap[0] = *(const frag8*)&sA[aoff[6]];
        ap[1] = *(const frag8*)&sA[aoff[7]];
        __builtin_amdgcn_s_setprio(1);
#pragma unroll
        for (int m = 0; m < 2; m++)
#pragma unroll
            for (int nf = 0; nf < 4; nf++)
                acc[6 + m][nf] = __builtin_amdgcn_mfma_f32_16x16x32_bf16(ap[m], b0[nf], acc[6 + m][nf], 0, 0, 0);
        __builtin_amdgcn_s_setprio(0);
        // ---- tile boundary: derived wait (next tile confirmed; newest prefetches stay in flight) ----
        if (t + 3 < nt)
            asm volatile("s_waitcnt vmcnt(8)" ::: "memory");
        else if (t + 2 < nt)
            asm volatile("s_waitcnt vmcnt(4)" ::: "memory");
        else
            asm volatile("s_waitcnt vmcnt(0)" ::: "memory");
        __builtin_amdgcn_s_barrier();
        __builtin_amdgcn_sched_barrier(0);
    }

    // ---- epilogue ----
    const int row0 = bm * 256 + wm * 128 + g4 * 4;
    const int col0 = bn * 256 + wn * 64 + l15;
    float* fout;
    if (EPI == 3) {
        const int z = blockIdx.z;
        fout = (z == 0) ? q0 : (z == 1) ? q1 : (z == 2) ? q2 : q3;
    } else {
        fout = (float*)Cout;
    }
#pragma unroll
    for (int nf = 0; nf < 4; nf++) {
        const int col = col0 + nf * 16;
        const float bv = (EPI == 3) ? 0.0f : bias[col];
#pragma unroll
        for (int mf = 0; mf < 8; mf++) {
#pragma unroll
            for (int r = 0; r < 4; r++) {
                const int row = row0 + mf * 16 + r;
                float v = acc[mf][nf][r] + bv;
                if (EPI == 2) v = gelu_exact(v);
                if (EPI == 0 || EPI == 3)
                    fout[(size_t)row * N + col] = v;
                else
                    ((u16*)Cout)[(size_t)row * N + col] = f2b(v);
            }
        }
    }
}

// ---------------- flash attention: 4 waves/block, 64 q-rows/block, KVBLK=64 ----------------
__global__ __launch_bounds__(256) void attn_kernel(const u16* __restrict__ qkv, u16* __restrict__ out) {
    __shared__ u16 kT[64 * 128];
    __shared__ u16 vT[128 * 72];
    const int h = blockIdx.y;
    const int qb = (int)gridDim.x - 1 - (int)blockIdx.x;  // heavy blocks first
    const int tid = threadIdx.x;
    const int lane = tid & 63, w = tid >> 6;
    const int l15 = lane & 15, g4 = lane >> 4;
    const int q0 = qb * 64 + w * 16;
    const float scale = 0.022097086912079608f;  // 1/sqrt(2048)

    frag8 qf[4];
    {
        const u16* qrow = qkv + (size_t)(q0 + l15) * N_QKV + h * HEAD_D + g4 * 8;
#pragma unroll
        for (int c = 0; c < 4; c++) qf[c] = *(const frag8*)(qrow + c * 32);
    }

    float m_run = -1e30f, l_run = 0.0f;
    facc4 o[8] = {};

    const int src0 = ((g4 & 1) << 5) + l15;
    const int src1 = src0 + 16;
    const bool hi = (g4 & 2) != 0;

    const int nt = qb + 1;
    for (int t = 0; t < nt; ++t) {
        const int kbase = t * 64;
        if (t) __syncthreads();
        const u16* kg_ptr = qkv + (size_t)kbase * N_QKV + D_MODEL + h * HEAD_D;
        const u16* vg_ptr = kg_ptr + D_MODEL;
        uint4 vv[4];
#pragma unroll
        for (int i = 0; i < 4; ++i)
            vv[i] = *(const uint4*)(vg_ptr + (size_t)lane * N_QKV + w * 32 + i * 8);
#pragma unroll
        for (int p = 0; p < 4; ++p) {
            const int c = p * 256 + tid;
            const int row = c >> 4;
            const int colb = (c & 15) << 4;
            const int srcb = colb ^ ((row & 7) << 4);
            gload_lds16(kg_ptr + (size_t)row * N_QKV + (srcb >> 1), &kT[c * 8]);
        }
#pragma unroll
        for (int i = 0; i < 4; ++i) {
            const u16* pv = (const u16*)&vv[i];
#pragma unroll
            for (int e = 0; e < 8; ++e)
                vT[(w * 32 + i * 8 + e) * 72 + lane] = pv[e];
        }
        __syncthreads();

        const bool last = (t == nt - 1);

        float st[16];
        float mx = -1e30f;
#pragma unroll
        for (int ks = 0; ks < 4; ++ks) {
            const bool active = !last || (ks <= w);
            if (active) {
                facc4 s = {};
                const int kl = ks * 16 + l15;
#pragma unroll
                for (int c = 0; c < 4; ++c) {
                    const int colb = (g4 * 16 + c * 64) ^ ((kl & 7) << 4);
                    frag8 kf = *(const frag8*)&kT[kl * 128 + (colb >> 1)];
                    s = __builtin_amdgcn_mfma_f32_16x16x32_bf16(kf, qf[c], s, 0, 0, 0);
                }
#pragma unroll
                for (int r = 0; r < 4; ++r) {
                    float v = s[r] * scale;
                    if (last) {
                        const int key = kbase + ks * 16 + g4 * 4 + r;
                        if (key > q0 + l15) v = -1e30f;
                    }
                    st[ks * 4 + r] = v;
                    mx = fmaxf(mx, v);
                }
            } else {
#pragma unroll
                for (int r = 0; r < 4; ++r) st[ks * 4 + r] = -1e30f;
            }
        }

        mx = fmaxf(mx, __shfl_xor(mx, 16));
        mx = fmaxf(mx, __shfl_xor(mx, 32));
        const float m_new = fmaxf(m_run, mx);
        const float alpha = __expf(m_run - m_new);
        float ps = 0.0f;
        uint2 pb[4];
#pragma unroll
        for (int ks = 0; ks < 4; ++ks) {
            const float p0 = __expf(st[ks * 4 + 0] - m_new);
            const float p1 = __expf(st[ks * 4 + 1] - m_new);
            const float p2 = __expf(st[ks * 4 + 2] - m_new);
            const float p3 = __expf(st[ks * 4 + 3] - m_new);
            ps += (p0 + p1) + (p2 + p3);
            pb[ks].x = (unsigned)f2b(p0) | ((unsigned)f2b(p1) << 16);
            pb[ks].y = (unsigned)f2b(p2) | ((unsigned)f2b(p3) << 16);
        }
        ps += __shfl_xor(ps, 16);
        ps += __shfl_xor(ps, 32);
        l_run = l_run * alpha + ps;
        m_run = m_new;
#pragma unroll
        for (int c8 = 0; c8 < 8; ++c8)
#pragma unroll
            for (int r = 0; r < 4; ++r) o[c8][r] *= alpha;

#pragma unroll
        for (int kp = 0; kp < 2; ++kp) {
            const bool kp_active = !last || (kp == 0) || (w >= 2);
            if (kp_active) {
                const uint2 a = pb[2 * kp], b = pb[2 * kp + 1];
                const unsigned a0 = __shfl(a.x, src0), a1 = __shfl(a.y, src0);
                const unsigned a2 = __shfl(a.x, src1), a3 = __shfl(a.y, src1);
                const unsigned b0 = __shfl(b.x, src0), b1 = __shfl(b.y, src0);
                const unsigned b2 = __shfl(b.x, src1), b3 = __shfl(b.y, src1);
                union { unsigned u[4]; frag8 f; } pu;
                pu.u[0] = hi ? b0 : a0;
                pu.u[1] = hi ? b1 : a1;
                pu.u[2] = hi ? b2 : a2;
                pu.u[3] = hi ? b3 : a3;
                const frag8 pf = pu.f;
#pragma unroll
                for (int c8 = 0; c8 < 8; ++c8) {
                    frag8 vf = *(const frag8*)&vT[(c8 * 16 + l15) * 72 + kp * 32 + g4 * 8];
                    o[c8] = __builtin_amdgcn_mfma_f32_16x16x32_bf16(vf, pf, o[c8], 0, 0, 0);
                }
            }
        }
    }

    const float inv_l = 1.0f / l_run;
    u16* orow = out + (size_t)(q0 + l15) * D_MODEL + h * HEAD_D;
#pragma unroll
    for (int c8 = 0; c8 < 8; ++c8) {
        uint2 st2;
        st2.x = (unsigned)f2b(o[c8][0] * inv_l) | ((unsigned)f2b(o[c8][1] * inv_l) << 16);
        st2.y = (unsigned)f2b(o[c8][2] * inv_l) | ((unsigned)f2b(o[c8][3] * inv_l) << 16);
        *(uint2*)&orow[c8 * 16 + g4 * 4] = st2;
    }
}

// ---------------- residual + layernorm -> bf16 ----------------
__global__ __launch_bounds__(256) void ln_kernel(const float* __restrict__ a, const float* __restrict__ b,
                                                 const float* __restrict__ gamma, const float* __restrict__ beta,
                                                 u16* __restrict__ outb) {
    __shared__ float red[8];
    const int row = blockIdx.x;
    const int tid = threadIdx.x;
    const float* pa = a + (size_t)row * D_MODEL;
    const float* pb = b + (size_t)row * D_MODEL;
    float v[8];
    float s = 0.0f, s2 = 0.0f;
#pragma unroll
    for (int i = 0; i < 8; i++) {
        const int c = tid + i * 256;
        const float x = pa[c] + pb[c];
        v[i] = x;
        s += x;
        s2 += x * x;
    }
#pragma unroll
    for (int off = 32; off; off >>= 1) {
        s += __shfl_xor(s, off);
        s2 += __shfl_xor(s2, off);
    }
    if ((tid & 63) == 0) { red[(tid >> 6) * 2] = s; red[(tid >> 6) * 2 + 1] = s2; }
    __syncthreads();
    s = red[0] + red[2] + red[4] + red[6];
    s2 = red[1] + red[3] + red[5] + red[7];
    const float mean = s * (1.0f / D_MODEL);
    const float var = s2 * (1.0f / D_MODEL) - mean * mean;
    const float rstd = rsqrtf(var + 1e-5f);
#pragma unroll
    for (int i = 0; i < 8; i++) {
        const int c = tid + i * 256;
        outb[(size_t)row * D_MODEL + c] = f2b((v[i] - mean) * rstd * gamma[c] + beta[c]);
    }
}

// ---------------- bf16 residual + Σ split-K partials + bias + layernorm -> f32 ----------------
__global__ __launch_bounds__(256) void ln_part_kernel(const u16* __restrict__ hb,
                                                      const float* __restrict__ p0, const float* __restrict__ p1,
                                                      const float* __restrict__ p2, const float* __restrict__ p3,
                                                      int np, const float* __restrict__ bias,
                                                      const float* __restrict__ gamma, const float* __restrict__ beta,
                                                      float* __restrict__ outf) {
    __shared__ float red[8];
    const int row = blockIdx.x;
    const int tid = threadIdx.x;
    const size_t rb = (size_t)row * D_MODEL;
    float v[8];
    float s = 0.0f, s2 = 0.0f;
#pragma unroll
    for (int i = 0; i < 8; i++) {
        const int c = tid + i * 256;
        float x = b2f(hb[rb + c]) + bias[c] + p0[rb + c] + p1[rb + c];
        if (np > 2) x += p2[rb + c];
        if (np > 3) x += p3[rb + c];
        v[i] = x;
        s += x;
        s2 += x * x;
    }
#pragma unroll
    for (int off = 32; off; off >>= 1) {
        s += __shfl_xor(s, off);
        s2 += __shfl_xor(s2, off);
    }
    if ((tid & 63) == 0) { red[(tid >> 6) * 2] = s; red[(tid >> 6) * 2 + 1] = s2; }
    __syncthreads();
    s = red[0] + red[2] + red[4] + red[6];
    s2 = red[1] + red[3] + red[5] + red[7];
    const float mean = s * (1.0f / D_MODEL);
    const float var = s2 * (1.0f / D_MODEL) - mean * mean;
    const float rstd = rsqrtf(var + 1e-5f);
#pragma unroll
    for (int i = 0; i < 8; i++) {
        const int c = tid + i * 256;
        outf[rb + c] = (v[i] - mean) * rstd * gamma[c] + beta[c];
    }
}

extern "C" void kernel_launch(void* const* d_in, const int* in_sizes, int n_in,
                              void* d_out, int out_size, void* d_ws, size_t ws_size,
                              hipStream_t stream) {
    const float* x    = (const float*)d_in[0];
    const float* Wqkv = (const float*)d_in[1];
    const float* bqkv = (const float*)d_in[2];
    const float* Wo   = (const float*)d_in[3];
    const float* bo   = (const float*)d_in[4];
    const float* W1   = (const float*)d_in[5];
    const float* b1   = (const float*)d_in[6];
    const float* W2   = (const float*)d_in[7];
    const float* b2   = (const float*)d_in[8];
    const float* g1   = (const float*)d_in[9];
    const float* be1  = (const float*)d_in[10];
    const float* g2   = (const float*)d_in[11];
    const float* be2  = (const float*)d_in[12];

    char* ws = (char*)d_ws;
    const size_t MB = 1024 * 1024;
    // layout (stream-ordered reuse; peak 120 MB, 136 MB if available):
    u16*  xb     = (u16*)(ws + 0);          // [0,8)
    u16*  WqkvT  = (u16*)(ws + 8 * MB);     // [8,32)
    u16*  qkv    = (u16*)(ws + 32 * MB);    // [32,56)
    u16*  attn_o = (u16*)(ws + 56 * MB);    // [56,64)
    u16*  WoT    = (u16*)(ws + 8 * MB);     // [8,16)   reuses WqkvT (dead)
    float* proj  = (float*)(ws + 16 * MB);  // [16,32)
    u16*  hb     = (u16*)(ws + 0);          // [0,8)    reuses xb (dead)
    u16*  W1T    = (u16*)(ws + 8 * MB);     // [8,40)   reuses WoT+proj (dead)
    u16*  f1     = (u16*)(ws + 40 * MB);    // [40,72)
    u16*  W2T    = (u16*)(ws + 72 * MB);    // [72,104)
    float* part0 = (float*)(ws + 8 * MB);   // [8,24)   reuses W1T (dead)
    float* part1 = (float*)(ws + 24 * MB);  // [24,40)
    float* part2 = (float*)(ws + 104 * MB); // [104,120)
    float* part3 = (float*)(ws + 120 * MB); // [120,136) only if ws >= 136 MB

    const int np = (ws_size >= 136 * MB) ? 4 : 3;
    const int kseg = (np == 4) ? 2048 : 2688;  // last z-plane takes remainder (2048 / 2816)

    const dim3 b32(32, 8);

    // 1. x -> bf16
    cvt_bf16_kernel<<<2048, 256, 0, stream>>>(x, xb, L_SEQ * D_MODEL);
    // 2. Wqkv^T
    tr_cvt_kernel<<<dim3(N_QKV / 32, D_MODEL / 32), b32, 0, stream>>>(Wqkv, WqkvT, D_MODEL, N_QKV);
    // 3. qkv = x @ Wqkv + bqkv (bf16), grid 192
    gemm256<1><<<dim3(192, 1, 1), 512, 0, stream>>>(xb, WqkvT, bqkv, qkv, nullptr, nullptr, nullptr, nullptr,
                                                    L_SEQ, N_QKV, D_MODEL, D_MODEL, 24);
    // 4. attention
    attn_kernel<<<dim3(L_SEQ / 64, N_HEADS), 256, 0, stream>>>(qkv, attn_o);
    // 5. Wo^T
    tr_cvt_kernel<<<dim3(D_MODEL / 32, D_MODEL / 32), b32, 0, stream>>>(Wo, WoT, D_MODEL, D_MODEL);
    // 6. proj = attn @ Wo + bo (f32)
    gemm_bt<<<dim3(D_MODEL / 128, L_SEQ / 128), 256, 0, stream>>>(attn_o, WoT, bo, proj, L_SEQ, D_MODEL, D_MODEL);
    // 7. hb = bf16(LN(x + proj))
    ln_kernel<<<L_SEQ, 256, 0, stream>>>(x, proj, g1, be1, hb);
    // 8. W1^T
    tr_cvt_kernel<<<dim3(D_INNER / 32, D_MODEL / 32), b32, 0, stream>>>(W1, W1T, D_MODEL, D_INNER);
    // 9. f1 = gelu(hb @ W1 + b1) (bf16), grid 256
    gemm256<2><<<dim3(256, 1, 1), 512, 0, stream>>>(hb, W1T, b1, f1, nullptr, nullptr, nullptr, nullptr,
                                                    L_SEQ, D_INNER, D_MODEL, D_MODEL, 32);
    // 10. W2^T
    tr_cvt_kernel<<<dim3(D_MODEL / 32, D_INNER / 32), b32, 0, stream>>>(W2, W2T, D_INNER, D_MODEL);
    // 11. f2 partials = f1 @ W2 (split-K=np, f32 planes)
    gemm256<3><<<dim3(64, 1, np), 512, 0, stream>>>(f1, W2T, nullptr, nullptr, part0, part1, part2, part3,
                                                    L_SEQ, D_MODEL, D_INNER, kseg, 8);
    // 12. out = LN(hb + Σparts + b2)*g2+be2
    ln_part_kernel<<<L_SEQ, 256, 0, stream>>>(hb, part0, part1, part2, part3, np, b2, g2, be2, (float*)d_out);
}

// Round 7
// 474.269 us; speedup vs baseline: 4.3464x; 1.0189x over previous
//
#include <hip/hip_runtime.h>
#include <hip/hip_bf16.h>

typedef unsigned short u16;
typedef __attribute__((ext_vector_type(8))) short frag8;   // 8 bf16
typedef __attribute__((ext_vector_type(4))) float facc4;   // 4 f32

#define L_SEQ 2048
#define D_MODEL 2048
#define N_HEADS 16
#define HEAD_D 128
#define N_QKV 6144
#define D_INNER 8192

__device__ __forceinline__ u16 f2b(float f) {
    __hip_bfloat16 h = __float2bfloat16(f);
    return *reinterpret_cast<u16*>(&h);
}

__device__ __forceinline__ float b2f(u16 u) {
    __hip_bfloat16 h = *reinterpret_cast<__hip_bfloat16*>(&u);
    return __bfloat162float(h);
}

__device__ __forceinline__ void gload_lds16(const void* g, void* l) {
    __builtin_amdgcn_global_load_lds(
        (const __attribute__((address_space(1))) unsigned int*)g,
        (__attribute__((address_space(3))) unsigned int*)l, 16, 0, 0);
}

__device__ __forceinline__ float gelu_exact(float x) {
    return 0.5f * x * (1.0f + erff(x * 0.7071067811865475f));
}

// ---------------- elementwise f32 -> bf16 ----------------
__global__ void cvt_bf16_kernel(const float* __restrict__ in, u16* __restrict__ out, int n) {
    int i = blockIdx.x * blockDim.x + threadIdx.x;
    int stride = gridDim.x * blockDim.x;
    for (; i < n; i += stride) out[i] = f2b(in[i]);
}

// ---------------- transpose + convert: in f32 [R][C] -> out bf16 [C][R] ----------------
__global__ void tr_cvt_kernel(const float* __restrict__ in, u16* __restrict__ out, int R, int C) {
    __shared__ float t[32][33];
    int bx = blockIdx.x * 32;  // C dim
    int by = blockIdx.y * 32;  // R dim
    int tx = threadIdx.x, ty = threadIdx.y;
#pragma unroll
    for (int k = 0; k < 32; k += 8) t[ty + k][tx] = in[(size_t)(by + ty + k) * C + bx + tx];
    __syncthreads();
#pragma unroll
    for (int k = 0; k < 32; k += 8) out[(size_t)(bx + ty + k) * R + by + tx] = f2b(t[tx][ty + k]);
}

// ---------------- legacy 128x128 GEMM (proj) ----------------
__global__ __launch_bounds__(256) void gemm_bt(const u16* __restrict__ A, const u16* __restrict__ Bt,
                                               const float* __restrict__ bias, float* __restrict__ Cout,
                                               int M, int N, int K) {
    __shared__ u16 lA[128 * 64];
    __shared__ u16 lB[128 * 64];
    const int tid = threadIdx.x;
    const int lane = tid & 63, wid = tid >> 6;
    const int wr = wid >> 1, wc = wid & 1;
    const int l15 = lane & 15, g4 = lane >> 4;
    const int bm = blockIdx.y, bn = blockIdx.x;

    const int arow = tid >> 3;
    const int acol = (tid & 7) * 8;
    const size_t abase = (size_t)(bm * 128) * K + acol;
    const size_t bbase = (size_t)(bn * 128) * K + acol;

    facc4 acc[4][4] = {};

    for (int k0 = 0; k0 < K; k0 += 64) {
        if (k0) __syncthreads();
#pragma unroll
        for (int i = 0; i < 4; i++) {
            gload_lds16(A + abase + (size_t)(i * 32 + arow) * K + k0, &lA[i * 2048 + tid * 8]);
            gload_lds16(Bt + bbase + (size_t)(i * 32 + arow) * K + k0, &lB[i * 2048 + tid * 8]);
        }
        __syncthreads();
#pragma unroll
        for (int kk = 0; kk < 64; kk += 32) {
            frag8 af[4], bf[4];
#pragma unroll
            for (int m = 0; m < 4; m++)
                af[m] = *(const frag8*)&lA[(wr * 64 + m * 16 + l15) * 64 + kk + g4 * 8];
#pragma unroll
            for (int n = 0; n < 4; n++)
                bf[n] = *(const frag8*)&lB[(wc * 64 + n * 16 + l15) * 64 + kk + g4 * 8];
#pragma unroll
            for (int m = 0; m < 4; m++)
#pragma unroll
                for (int n = 0; n < 4; n++)
                    acc[m][n] = __builtin_amdgcn_mfma_f32_16x16x32_bf16(af[m], bf[n], acc[m][n], 0, 0, 0);
        }
    }

    const int row0 = bm * 128 + wr * 64 + g4 * 4;
    const int col0 = bn * 128 + wc * 64 + l15;
#pragma unroll
    for (int n = 0; n < 4; n++) {
        const int col = col0 + n * 16;
        const float bv = bias[col];
#pragma unroll
        for (int m = 0; m < 4; m++)
#pragma unroll
            for (int r = 0; r < 4; r++)
                Cout[(size_t)(row0 + m * 16 + r) * N + col] = acc[m][n][r] + bv;
    }
}

// ---------------- gemm256 v6: 256x256 tile, BK=32, ring-4 LDS (128 KiB), sub-phased reads ----------------
// EPI: 0 f32+bias, 1 bf16+bias, 2 gelu+bf16+bias, 3 f32 partial (plane by blockIdx.z, no bias)
template <int EPI>
__global__ __launch_bounds__(512, 2) void gemm256(const u16* __restrict__ A, const u16* __restrict__ Bt,
                                                  const float* __restrict__ bias, void* __restrict__ Cout,
                                                  float* __restrict__ q0, float* __restrict__ q1,
                                                  float* __restrict__ q2, float* __restrict__ q3,
                                                  int M, int N, int K, int kseg, int nbn) {
    __shared__ u16 lds[4 * 16384];  // stage s: A at s*16384, B at s*16384+8192 (u16 units)
    const int tid = threadIdx.x;
    const int lane = tid & 63, wid = tid >> 6;
    const int wm = wid >> 2, wn = wid & 3;
    const int l15 = lane & 15, g4 = lane >> 4;

    // XCD-chunked block swizzle (grids have nwg % 8 == 0)
    const int nwg = gridDim.x;
    const int q8 = nwg >> 3;
    const int wg = (blockIdx.x & 7) * q8 + (blockIdx.x >> 3);
    const int bn = wg % nbn, bm = wg / nbn;
    const int kb = blockIdx.z * kseg;
    const int ksz = (blockIdx.z == (int)gridDim.z - 1) ? (K - kb) : kseg;
    const int nt = ksz >> 5;

    // staging: thread covers rows (tid>>2, +128), 16B chunk (tid&3); source pre-swizzled
    const int rA = tid >> 2;
    const int swzT = ((tid >> 3) & 3) << 4;             // ((rA>>1)&3)<<4  (bytes)
    const int srcE = ((((tid & 3) << 4) ^ swzT) >> 1);  // source elem offset within 32-elem row
    const u16* Ab = A + (size_t)(bm * 256 + rA) * K + kb + srcE;
    const u16* Bb = Bt + (size_t)(bn * 256 + rA) * K + kb + srcE;
    const size_t rstride = (size_t)128 * K;

    // fragment read offsets (u16 units), swizzle applied
    int aoff[8], boff[4];
#pragma unroll
    for (int mf = 0; mf < 8; mf++) {
        const int rowl = wm * 128 + mf * 16 + l15;
        aoff[mf] = rowl * 32 + (((g4 * 16) ^ (((rowl >> 1) & 3) << 4)) >> 1);
    }
#pragma unroll
    for (int nf = 0; nf < 4; nf++) {
        const int rowl = wn * 64 + nf * 16 + l15;
        boff[nf] = rowl * 32 + (((g4 * 16) ^ (((rowl >> 1) & 3) << 4)) >> 1);
    }

    auto stageA = [&](int tt) {
        u16* sA = &lds[(tt & 3) * 16384];
        const u16* g = Ab + (size_t)tt * 32;
        gload_lds16(g, sA + tid * 8);
        gload_lds16(g + rstride, sA + 4096 + tid * 8);
    };
    auto stageB = [&](int tt) {
        u16* sB = &lds[(tt & 3) * 16384 + 8192];
        const u16* g = Bb + (size_t)tt * 32;
        gload_lds16(g, sB + tid * 8);
        gload_lds16(g + rstride, sB + 4096 + tid * 8);
    };

    facc4 acc[8][4] = {};

    // prologue: stage tiles 0,1,2; confirm tile 0 (8 newest stay in flight)
    stageA(0); stageB(0);
    stageA(1); stageB(1);
    stageA(2); stageB(2);
    asm volatile("s_waitcnt vmcnt(8)" ::: "memory");
    __builtin_amdgcn_s_barrier();
    __builtin_amdgcn_sched_barrier(0);

    for (int t = 0; t < nt; ++t) {
        const u16* sA = &lds[(t & 3) * 16384];
        const u16* sB = sA + 8192;
        // ---- s0: B frags + A 0,1 ----
        frag8 b0[4], ap[2];
#pragma unroll
        for (int i = 0; i < 4; i++) b0[i] = *(const frag8*)&sB[boff[i]];
        ap[0] = *(const frag8*)&sA[aoff[0]];
        ap[1] = *(const frag8*)&sA[aoff[1]];
        if (t + 3 < nt) stageA(t + 3);
        __builtin_amdgcn_s_setprio(1);
#pragma unroll
        for (int m = 0; m < 2; m++)
#pragma unroll
            for (int nf = 0; nf < 4; nf++)
                acc[m][nf] = __builtin_amdgcn_mfma_f32_16x16x32_bf16(ap[m], b0[nf], acc[m][nf], 0, 0, 0);
        __builtin_amdgcn_s_setprio(0);
        // ---- s1: A 2,3 ----
        ap[0] = *(const frag8*)&sA[aoff[2]];
        ap[1] = *(const frag8*)&sA[aoff[3]];
        __builtin_amdgcn_s_setprio(1);
#pragma unroll
        for (int m = 0; m < 2; m++)
#pragma unroll
            for (int nf = 0; nf < 4; nf++)
                acc[2 + m][nf] = __builtin_amdgcn_mfma_f32_16x16x32_bf16(ap[m], b0[nf], acc[2 + m][nf], 0, 0, 0);
        __builtin_amdgcn_s_setprio(0);
        __builtin_amdgcn_s_barrier();  // mid-tile barrier
        // ---- s2: A 4,5 ----
        ap[0] = *(const frag8*)&sA[aoff[4]];
        ap[1] = *(const frag8*)&sA[aoff[5]];
        if (t + 3 < nt) stageB(t + 3);
        __builtin_amdgcn_s_setprio(1);
#pragma unroll
        for (int m = 0; m < 2; m++)
#pragma unroll
            for (int nf = 0; nf < 4; nf++)
                acc[4 + m][nf] = __builtin_amdgcn_mfma_f32_16x16x32_bf16(ap[m], b0[nf], acc[4 + m][nf], 0, 0, 0);
        __builtin_amdgcn_s_setprio(0);
        // ---- s3: A 6,7 ----
        ap[0] = *(const frag8*)&sA[aoff[6]];
        ap[1] = *(const frag8*)&sA[aoff[7]];
        __builtin_amdgcn_s_setprio(1);
#pragma unroll
        for (int m = 0; m < 2; m++)
#pragma unroll
            for (int nf = 0; nf < 4; nf++)
                acc[6 + m][nf] = __builtin_amdgcn_mfma_f32_16x16x32_bf16(ap[m], b0[nf], acc[6 + m][nf], 0, 0, 0);
        __builtin_amdgcn_s_setprio(0);
        // ---- tile boundary: derived wait ----
        if (t + 3 < nt)
            asm volatile("s_waitcnt vmcnt(8)" ::: "memory");
        else if (t + 2 < nt)
            asm volatile("s_waitcnt vmcnt(4)" ::: "memory");
        else
            asm volatile("s_waitcnt vmcnt(0)" ::: "memory");
        __builtin_amdgcn_s_barrier();
        __builtin_amdgcn_sched_barrier(0);
    }

    // ---- epilogue ----
    const int row0 = bm * 256 + wm * 128 + g4 * 4;
    const int col0 = bn * 256 + wn * 64 + l15;
    float* fout;
    if (EPI == 3) {
        const int z = blockIdx.z;
        fout = (z == 0) ? q0 : (z == 1) ? q1 : (z == 2) ? q2 : q3;
    } else {
        fout = (float*)Cout;
    }
#pragma unroll
    for (int nf = 0; nf < 4; nf++) {
        const int col = col0 + nf * 16;
        const float bv = (EPI == 3) ? 0.0f : bias[col];
#pragma unroll
        for (int mf = 0; mf < 8; mf++) {
#pragma unroll
            for (int r = 0; r < 4; r++) {
                const int row = row0 + mf * 16 + r;
                float v = acc[mf][nf][r] + bv;
                if (EPI == 2) v = gelu_exact(v);
                if (EPI == 0 || EPI == 3)
                    fout[(size_t)row * N + col] = v;
                else
                    ((u16*)Cout)[(size_t)row * N + col] = f2b(v);
            }
        }
    }
}

// ---------------- flash attention v7: 4 waves/block, 64 q-rows/block, KVBLK=64 ----------------
// v7: (a) balanced complementary qb pairing; (b) V tile [128][64] with 16B-chunk XOR swizzle
// (write+read same involution, banks = chunk'*4 -> conflict-free); (c) T13 defer-max rescale.
__global__ __launch_bounds__(256) void attn_kernel(const u16* __restrict__ qkv, u16* __restrict__ out) {
    __shared__ u16 kT[64 * 128];
    __shared__ u16 vT[128 * 64];
    const int h = blockIdx.y;
    // complementary pairing: blocks i and i+256 (same bx, by^8) get qb summing to 31
    const int qb = (blockIdx.y < 8) ? ((int)gridDim.x - 1 - (int)blockIdx.x) : (int)blockIdx.x;
    const int tid = threadIdx.x;
    const int lane = tid & 63, w = tid >> 6;
    const int l15 = lane & 15, g4 = lane >> 4;
    const int q0 = qb * 64 + w * 16;
    const float scale = 0.022097086912079608f;  // 1/sqrt(2048)

    frag8 qf[4];
    {
        const u16* qrow = qkv + (size_t)(q0 + l15) * N_QKV + h * HEAD_D + g4 * 8;
#pragma unroll
        for (int c = 0; c < 4; c++) qf[c] = *(const frag8*)(qrow + c * 32);
    }

    float m_run = -1e30f, l_run = 0.0f;
    facc4 o[8] = {};

    const int src0 = ((g4 & 1) << 5) + l15;
    const int src1 = src0 + 16;
    const bool hi = (g4 & 2) != 0;

    const int nt = qb + 1;
    for (int t = 0; t < nt; ++t) {
        const int kbase = t * 64;
        if (t) __syncthreads();
        const u16* kg_ptr = qkv + (size_t)kbase * N_QKV + D_MODEL + h * HEAD_D;
        const u16* vg_ptr = kg_ptr + D_MODEL;
        uint4 vv[4];
#pragma unroll
        for (int i = 0; i < 4; ++i)
            vv[i] = *(const uint4*)(vg_ptr + (size_t)lane * N_QKV + w * 32 + i * 8);
#pragma unroll
        for (int p = 0; p < 4; ++p) {
            const int c = p * 256 + tid;
            const int row = c >> 4;
            const int colb = (c & 15) << 4;
            const int srcb = colb ^ ((row & 7) << 4);
            gload_lds16(kg_ptr + (size_t)row * N_QKV + (srcb >> 1), &kT[c * 8]);
        }
        // V transpose-write, XOR-swizzled 16B chunks: elem (d=row, key=lane) at
        // vT[d*64 + (((key>>3)^(d&7))<<3) + (key&7)]  (conflict-free write & read)
#pragma unroll
        for (int i = 0; i < 4; ++i) {
            const u16* pv = (const u16*)&vv[i];
#pragma unroll
            for (int e = 0; e < 8; ++e) {
                const int d = w * 32 + i * 8 + e;
                vT[d * 64 + ((((lane >> 3) ^ (d & 7)) << 3) | (lane & 7))] = pv[e];
            }
        }
        __syncthreads();

        const bool last = (t == nt - 1);

        float st[16];
        float mx = -1e30f;
#pragma unroll
        for (int ks = 0; ks < 4; ++ks) {
            const bool active = !last || (ks <= w);
            if (active) {
                facc4 s = {};
                const int kl = ks * 16 + l15;
#pragma unroll
                for (int c = 0; c < 4; ++c) {
                    const int colb = (g4 * 16 + c * 64) ^ ((kl & 7) << 4);
                    frag8 kf = *(const frag8*)&kT[kl * 128 + (colb >> 1)];
                    s = __builtin_amdgcn_mfma_f32_16x16x32_bf16(kf, qf[c], s, 0, 0, 0);
                }
#pragma unroll
                for (int r = 0; r < 4; ++r) {
                    float v = s[r] * scale;
                    if (last) {
                        const int key = kbase + ks * 16 + g4 * 4 + r;
                        if (key > q0 + l15) v = -1e30f;
                    }
                    st[ks * 4 + r] = v;
                    mx = fmaxf(mx, v);
                }
            } else {
#pragma unroll
                for (int r = 0; r < 4; ++r) st[ks * 4 + r] = -1e30f;
            }
        }

        mx = fmaxf(mx, __shfl_xor(mx, 16));
        mx = fmaxf(mx, __shfl_xor(mx, 32));
        // T13 defer-max: skip O-rescale when tile max growth <= 8 (P bounded by e^8)
        const bool skip = __all(mx <= m_run + 8.0f);
        const float m_new = skip ? m_run : fmaxf(m_run, mx);
        const float alpha = __expf(m_run - m_new);  // == 1 when skip
        float ps = 0.0f;
        uint2 pb[4];
#pragma unroll
        for (int ks = 0; ks < 4; ++ks) {
            const float p0 = __expf(st[ks * 4 + 0] - m_new);
            const float p1 = __expf(st[ks * 4 + 1] - m_new);
            const float p2 = __expf(st[ks * 4 + 2] - m_new);
            const float p3 = __expf(st[ks * 4 + 3] - m_new);
            ps += (p0 + p1) + (p2 + p3);
            pb[ks].x = (unsigned)f2b(p0) | ((unsigned)f2b(p1) << 16);
            pb[ks].y = (unsigned)f2b(p2) | ((unsigned)f2b(p3) << 16);
        }
        ps += __shfl_xor(ps, 16);
        ps += __shfl_xor(ps, 32);
        l_run = l_run * alpha + ps;
        m_run = m_new;
        if (!skip) {
#pragma unroll
            for (int c8 = 0; c8 < 8; ++c8)
#pragma unroll
                for (int r = 0; r < 4; ++r) o[c8][r] *= alpha;
        }

#pragma unroll
        for (int kp = 0; kp < 2; ++kp) {
            const bool kp_active = !last || (kp == 0) || (w >= 2);
            if (kp_active) {
                const uint2 a = pb[2 * kp], b = pb[2 * kp + 1];
                const unsigned a0 = __shfl(a.x, src0), a1 = __shfl(a.y, src0);
                const unsigned a2 = __shfl(a.x, src1), a3 = __shfl(a.y, src1);
                const unsigned b0 = __shfl(b.x, src0), b1 = __shfl(b.y, src0);
                const unsigned b2 = __shfl(b.x, src1), b3 = __shfl(b.y, src1);
                union { unsigned u[4]; frag8 f; } pu;
                pu.u[0] = hi ? b0 : a0;
                pu.u[1] = hi ? b1 : a1;
                pu.u[2] = hi ? b2 : a2;
                pu.u[3] = hi ? b3 : a3;
                const frag8 pf = pu.f;
#pragma unroll
                for (int c8 = 0; c8 < 8; ++c8) {
                    const int d = c8 * 16 + l15;
                    const int ch = (((kp * 4 + g4) ^ (l15 & 7)) << 3);
                    frag8 vf = *(const frag8*)&vT[d * 64 + ch];
                    o[c8] = __builtin_amdgcn_mfma_f32_16x16x32_bf16(vf, pf, o[c8], 0, 0, 0);
                }
            }
        }
    }

    const float inv_l = 1.0f / l_run;
    u16* orow = out + (size_t)(q0 + l15) * D_MODEL + h * HEAD_D;
#pragma unroll
    for (int c8 = 0; c8 < 8; ++c8) {
        uint2 st2;
        st2.x = (unsigned)f2b(o[c8][0] * inv_l) | ((unsigned)f2b(o[c8][1] * inv_l) << 16);
        st2.y = (unsigned)f2b(o[c8][2] * inv_l) | ((unsigned)f2b(o[c8][3] * inv_l) << 16);
        *(uint2*)&orow[c8 * 16 + g4 * 4] = st2;
    }
}

// ---------------- residual + layernorm -> bf16 ----------------
__global__ __launch_bounds__(256) void ln_kernel(const float* __restrict__ a, const float* __restrict__ b,
                                                 const float* __restrict__ gamma, const float* __restrict__ beta,
                                                 u16* __restrict__ outb) {
    __shared__ float red[8];
    const int row = blockIdx.x;
    const int tid = threadIdx.x;
    const float* pa = a + (size_t)row * D_MODEL;
    const float* pb = b + (size_t)row * D_MODEL;
    float v[8];
    float s = 0.0f, s2 = 0.0f;
#pragma unroll
    for (int i = 0; i < 8; i++) {
        const int c = tid + i * 256;
        const float x = pa[c] + pb[c];
        v[i] = x;
        s += x;
        s2 += x * x;
    }
#pragma unroll
    for (int off = 32; off; off >>= 1) {
        s += __shfl_xor(s, off);
        s2 += __shfl_xor(s2, off);
    }
    if ((tid & 63) == 0) { red[(tid >> 6) * 2] = s; red[(tid >> 6) * 2 + 1] = s2; }
    __syncthreads();
    s = red[0] + red[2] + red[4] + red[6];
    s2 = red[1] + red[3] + red[5] + red[7];
    const float mean = s * (1.0f / D_MODEL);
    const float var = s2 * (1.0f / D_MODEL) - mean * mean;
    const float rstd = rsqrtf(var + 1e-5f);
#pragma unroll
    for (int i = 0; i < 8; i++) {
        const int c = tid + i * 256;
        outb[(size_t)row * D_MODEL + c] = f2b((v[i] - mean) * rstd * gamma[c] + beta[c]);
    }
}

// ---------------- bf16 residual + Σ split-K partials + bias + layernorm -> f32 ----------------
__global__ __launch_bounds__(256) void ln_part_kernel(const u16* __restrict__ hb,
                                                      const float* __restrict__ p0, const float* __restrict__ p1,
                                                      const float* __restrict__ p2, const float* __restrict__ p3,
                                                      int np, const float* __restrict__ bias,
                                                      const float* __restrict__ gamma, const float* __restrict__ beta,
                                                      float* __restrict__ outf) {
    __shared__ float red[8];
    const int row = blockIdx.x;
    const int tid = threadIdx.x;
    const size_t rb = (size_t)row * D_MODEL;
    float v[8];
    float s = 0.0f, s2 = 0.0f;
#pragma unroll
    for (int i = 0; i < 8; i++) {
        const int c = tid + i * 256;
        float x = b2f(hb[rb + c]) + bias[c] + p0[rb + c] + p1[rb + c];
        if (np > 2) x += p2[rb + c];
        if (np > 3) x += p3[rb + c];
        v[i] = x;
        s += x;
        s2 += x * x;
    }
#pragma unroll
    for (int off = 32; off; off >>= 1) {
        s += __shfl_xor(s, off);
        s2 += __shfl_xor(s2, off);
    }
    if ((tid & 63) == 0) { red[(tid >> 6) * 2] = s; red[(tid >> 6) * 2 + 1] = s2; }
    __syncthreads();
    s = red[0] + red[2] + red[4] + red[6];
    s2 = red[1] + red[3] + red[5] + red[7];
    const float mean = s * (1.0f / D_MODEL);
    const float var = s2 * (1.0f / D_MODEL) - mean * mean;
    const float rstd = rsqrtf(var + 1e-5f);
#pragma unroll
    for (int i = 0; i < 8; i++) {
        const int c = tid + i * 256;
        outf[rb + c] = (v[i] - mean) * rstd * gamma[c] + beta[c];
    }
}

extern "C" void kernel_launch(void* const* d_in, const int* in_sizes, int n_in,
                              void* d_out, int out_size, void* d_ws, size_t ws_size,
                              hipStream_t stream) {
    const float* x    = (const float*)d_in[0];
    const float* Wqkv = (const float*)d_in[1];
    const float* bqkv = (const float*)d_in[2];
    const float* Wo   = (const float*)d_in[3];
    const float* bo   = (const float*)d_in[4];
    const float* W1   = (const float*)d_in[5];
    const float* b1   = (const float*)d_in[6];
    const float* W2   = (const float*)d_in[7];
    const float* b2   = (const float*)d_in[8];
    const float* g1   = (const float*)d_in[9];
    const float* be1  = (const float*)d_in[10];
    const float* g2   = (const float*)d_in[11];
    const float* be2  = (const float*)d_in[12];

    char* ws = (char*)d_ws;
    const size_t MB = 1024 * 1024;
    // layout (stream-ordered reuse; peak 120 MB, 136 MB if available):
    u16*  xb     = (u16*)(ws + 0);          // [0,8)
    u16*  WqkvT  = (u16*)(ws + 8 * MB);     // [8,32)
    u16*  qkv    = (u16*)(ws + 32 * MB);    // [32,56)
    u16*  attn_o = (u16*)(ws + 56 * MB);    // [56,64)
    u16*  WoT    = (u16*)(ws + 8 * MB);     // [8,16)   reuses WqkvT (dead)
    float* proj  = (float*)(ws + 16 * MB);  // [16,32)
    u16*  hb     = (u16*)(ws + 0);          // [0,8)    reuses xb (dead)
    u16*  W1T    = (u16*)(ws + 8 * MB);     // [8,40)   reuses WoT+proj (dead)
    u16*  f1     = (u16*)(ws + 40 * MB);    // [40,72)
    u16*  W2T    = (u16*)(ws + 72 * MB);    // [72,104)
    float* part0 = (float*)(ws + 8 * MB);   // [8,24)   reuses W1T (dead)
    float* part1 = (float*)(ws + 24 * MB);  // [24,40)
    float* part2 = (float*)(ws + 104 * MB); // [104,120)
    float* part3 = (float*)(ws + 120 * MB); // [120,136) only if ws >= 136 MB

    const int np = (ws_size >= 136 * MB) ? 4 : 3;
    const int kseg = (np == 4) ? 2048 : 2688;  // last z-plane takes remainder

    const dim3 b32(32, 8);

    // 1. x -> bf16
    cvt_bf16_kernel<<<2048, 256, 0, stream>>>(x, xb, L_SEQ * D_MODEL);
    // 2. Wqkv^T
    tr_cvt_kernel<<<dim3(N_QKV / 32, D_MODEL / 32), b32, 0, stream>>>(Wqkv, WqkvT, D_MODEL, N_QKV);
    // 3. qkv = x @ Wqkv + bqkv (bf16), grid 192
    gemm256<1><<<dim3(192, 1, 1), 512, 0, stream>>>(xb, WqkvT, bqkv, qkv, nullptr, nullptr, nullptr, nullptr,
                                                    L_SEQ, N_QKV, D_MODEL, D_MODEL, 24);
    // 4. attention
    attn_kernel<<<dim3(L_SEQ / 64, N_HEADS), 256, 0, stream>>>(qkv, attn_o);
    // 5. Wo^T
    tr_cvt_kernel<<<dim3(D_MODEL / 32, D_MODEL / 32), b32, 0, stream>>>(Wo, WoT, D_MODEL, D_MODEL);
    // 6. proj = attn @ Wo + bo (f32)
    gemm_bt<<<dim3(D_MODEL / 128, L_SEQ / 128), 256, 0, stream>>>(attn_o, WoT, bo, proj, L_SEQ, D_MODEL, D_MODEL);
    // 7. hb = bf16(LN(x + proj))
    ln_kernel<<<L_SEQ, 256, 0, stream>>>(x, proj, g1, be1, hb);
    // 8. W1^T
    tr_cvt_kernel<<<dim3(D_INNER / 32, D_MODEL / 32), b32, 0, stream>>>(W1, W1T, D_MODEL, D_INNER);
    // 9. f1 = gelu(hb @ W1 + b1) (bf16), grid 256
    gemm256<2><<<dim3(256, 1, 1), 512, 0, stream>>>(hb, W1T, b1, f1, nullptr, nullptr, nullptr, nullptr,
                                                    L_SEQ, D_INNER, D_MODEL, D_MODEL, 32);
    // 10. W2^T
    tr_cvt_kernel<<<dim3(D_MODEL / 32, D_INNER / 32), b32, 0, stream>>>(W2, W2T, D_INNER, D_MODEL);
    // 11. f2 partials = f1 @ W2 (split-K=np, f32 planes)
    gemm256<3><<<dim3(64, 1, np), 512, 0, stream>>>(f1, W2T, nullptr, nullptr, part0, part1, part2, part3,
                                                    L_SEQ, D_MODEL, D_INNER, kseg, 8);
    // 12. out = LN(hb + Σparts + b2)*g2+be2
    ln_part_kernel<<<L_SEQ, 256, 0, stream>>>(hb, part0, part1, part2, part3, np, b2, g2, be2, (float*)d_out);
}

// Round 8
// 472.247 us; speedup vs baseline: 4.3650x; 1.0043x over previous
//
#include <hip/hip_runtime.h>
#include <hip/hip_bf16.h>

typedef unsigned short u16;
typedef __attribute__((ext_vector_type(8))) short frag8;   // 8 bf16
typedef __attribute__((ext_vector_type(4))) float facc4;   // 4 f32

#define L_SEQ 2048
#define D_MODEL 2048
#define N_HEADS 16
#define HEAD_D 128
#define N_QKV 6144
#define D_INNER 8192

__device__ __forceinline__ u16 f2b(float f) {
    __hip_bfloat16 h = __float2bfloat16(f);
    return *reinterpret_cast<u16*>(&h);
}

__device__ __forceinline__ float b2f(u16 u) {
    __hip_bfloat16 h = *reinterpret_cast<__hip_bfloat16*>(&u);
    return __bfloat162float(h);
}

__device__ __forceinline__ void gload_lds16(const void* g, void* l) {
    __builtin_amdgcn_global_load_lds(
        (const __attribute__((address_space(1))) unsigned int*)g,
        (__attribute__((address_space(3))) unsigned int*)l, 16, 0, 0);
}

__device__ __forceinline__ float gelu_exact(float x) {
    return 0.5f * x * (1.0f + erff(x * 0.7071067811865475f));
}

// ---------------- elementwise f32 -> bf16 (vectorized, n multiple of 2048) ----------------
__global__ __launch_bounds__(256) void cvt_bf16_kernel(const float* __restrict__ in, u16* __restrict__ out, int n) {
    const int i = (blockIdx.x * 256 + threadIdx.x) * 8;
    if (i >= n) return;
    float4 a = *(const float4*)(in + i);
    float4 b = *(const float4*)(in + i + 4);
    u16 tmp[8];
    tmp[0] = f2b(a.x); tmp[1] = f2b(a.y); tmp[2] = f2b(a.z); tmp[3] = f2b(a.w);
    tmp[4] = f2b(b.x); tmp[5] = f2b(b.y); tmp[6] = f2b(b.z); tmp[7] = f2b(b.w);
    *(uint4*)(out + i) = *(uint4*)tmp;
}

// ---------------- transpose + convert v2: in f32 [R][C] -> out bf16 [C][R], 64x64 tiles ----------------
// Reads: float4 x4/thread (256B contiguous per 4 lanes). Writes: 2x uint4 bf16 (32B/thread).
__global__ __launch_bounds__(256) void tr_cvt64(const float* __restrict__ in, u16* __restrict__ out, int R, int C) {
    __shared__ float t[64][68];  // stride 68: float4-aligned rows
    const int bx = blockIdx.x * 64;  // C dim
    const int by = blockIdx.y * 64;  // R dim
    const int tid = threadIdx.x;
    {
        const int r = tid >> 2;          // 0..63
        const int c4 = (tid & 3) * 16;   // 0,16,32,48
        const float* src = in + (size_t)(by + r) * C + bx + c4;
#pragma unroll
        for (int j = 0; j < 4; ++j)
            *(float4*)&t[r][c4 + 4 * j] = *(const float4*)(src + 4 * j);
    }
    __syncthreads();
    {
        const int cc = tid >> 2;          // 0..63 (C dim within tile)
        const int rr0 = (tid & 3) * 16;   // 0,16,32,48 (R dim within tile)
        u16 tmp[16];
#pragma unroll
        for (int j = 0; j < 16; ++j) tmp[j] = f2b(t[rr0 + j][cc]);
        u16* dst = out + (size_t)(bx + cc) * R + by + rr0;
        *(uint4*)(dst) = *(uint4*)&tmp[0];
        *(uint4*)(dst + 8) = *(uint4*)&tmp[8];
    }
}

// ---------------- legacy 128x128 GEMM (proj) ----------------
__global__ __launch_bounds__(256) void gemm_bt(const u16* __restrict__ A, const u16* __restrict__ Bt,
                                               const float* __restrict__ bias, float* __restrict__ Cout,
                                               int M, int N, int K) {
    __shared__ u16 lA[128 * 64];
    __shared__ u16 lB[128 * 64];
    const int tid = threadIdx.x;
    const int lane = tid & 63, wid = tid >> 6;
    const int wr = wid >> 1, wc = wid & 1;
    const int l15 = lane & 15, g4 = lane >> 4;
    const int bm = blockIdx.y, bn = blockIdx.x;

    const int arow = tid >> 3;
    const int acol = (tid & 7) * 8;
    const size_t abase = (size_t)(bm * 128) * K + acol;
    const size_t bbase = (size_t)(bn * 128) * K + acol;

    facc4 acc[4][4] = {};

    for (int k0 = 0; k0 < K; k0 += 64) {
        if (k0) __syncthreads();
#pragma unroll
        for (int i = 0; i < 4; i++) {
            gload_lds16(A + abase + (size_t)(i * 32 + arow) * K + k0, &lA[i * 2048 + tid * 8]);
            gload_lds16(Bt + bbase + (size_t)(i * 32 + arow) * K + k0, &lB[i * 2048 + tid * 8]);
        }
        __syncthreads();
#pragma unroll
        for (int kk = 0; kk < 64; kk += 32) {
            frag8 af[4], bf[4];
#pragma unroll
            for (int m = 0; m < 4; m++)
                af[m] = *(const frag8*)&lA[(wr * 64 + m * 16 + l15) * 64 + kk + g4 * 8];
#pragma unroll
            for (int n = 0; n < 4; n++)
                bf[n] = *(const frag8*)&lB[(wc * 64 + n * 16 + l15) * 64 + kk + g4 * 8];
#pragma unroll
            for (int m = 0; m < 4; m++)
#pragma unroll
                for (int n = 0; n < 4; n++)
                    acc[m][n] = __builtin_amdgcn_mfma_f32_16x16x32_bf16(af[m], bf[n], acc[m][n], 0, 0, 0);
        }
    }

    const int row0 = bm * 128 + wr * 64 + g4 * 4;
    const int col0 = bn * 128 + wc * 64 + l15;
#pragma unroll
    for (int n = 0; n < 4; n++) {
        const int col = col0 + n * 16;
        const float bv = bias[col];
#pragma unroll
        for (int m = 0; m < 4; m++)
#pragma unroll
            for (int r = 0; r < 4; r++)
                Cout[(size_t)(row0 + m * 16 + r) * N + col] = acc[m][n][r] + bv;
    }
}

// ---------------- gemm256 v8: 256x256 tile, BK=32, ring-4 LDS, sub-phased, bm-minor XCD mapping ----------------
// bm-minor: per-XCD concurrent blocks share few B panels (L2-resident) -> staging loads hit L2.
// EPI: 0 f32+bias, 1 bf16+bias, 2 gelu+bf16+bias, 3 f32 partial (plane by blockIdx.z, no bias)
template <int EPI>
__global__ __launch_bounds__(512, 2) void gemm256(const u16* __restrict__ A, const u16* __restrict__ Bt,
                                                  const float* __restrict__ bias, void* __restrict__ Cout,
                                                  float* __restrict__ q0, float* __restrict__ q1,
                                                  float* __restrict__ q2, float* __restrict__ q3,
                                                  int M, int N, int K, int kseg, int nbm) {
    __shared__ u16 lds[4 * 16384];  // stage s: A at s*16384, B at s*16384+8192 (u16 units)
    const int tid = threadIdx.x;
    const int lane = tid & 63, wid = tid >> 6;
    const int wm = wid >> 2, wn = wid & 3;
    const int l15 = lane & 15, g4 = lane >> 4;

    // XCD-chunked block swizzle (grids have nwg % 8 == 0); bm-minor within each XCD chunk
    const int nwg = gridDim.x;
    const int q8 = nwg >> 3;
    const int wg = (blockIdx.x & 7) * q8 + (blockIdx.x >> 3);
    const int bm = wg % nbm, bn = wg / nbm;
    const int kb = blockIdx.z * kseg;
    const int ksz = (blockIdx.z == (int)gridDim.z - 1) ? (K - kb) : kseg;
    const int nt = ksz >> 5;

    // staging: thread covers rows (tid>>2, +128), 16B chunk (tid&3); source pre-swizzled
    const int rA = tid >> 2;
    const int swzT = ((tid >> 3) & 3) << 4;             // ((rA>>1)&3)<<4  (bytes)
    const int srcE = ((((tid & 3) << 4) ^ swzT) >> 1);  // source elem offset within 32-elem row
    const u16* Ab = A + (size_t)(bm * 256 + rA) * K + kb + srcE;
    const u16* Bb = Bt + (size_t)(bn * 256 + rA) * K + kb + srcE;
    const size_t rstride = (size_t)128 * K;

    // fragment read offsets (u16 units), swizzle applied
    int aoff[8], boff[4];
#pragma unroll
    for (int mf = 0; mf < 8; mf++) {
        const int rowl = wm * 128 + mf * 16 + l15;
        aoff[mf] = rowl * 32 + (((g4 * 16) ^ (((rowl >> 1) & 3) << 4)) >> 1);
    }
#pragma unroll
    for (int nf = 0; nf < 4; nf++) {
        const int rowl = wn * 64 + nf * 16 + l15;
        boff[nf] = rowl * 32 + (((g4 * 16) ^ (((rowl >> 1) & 3) << 4)) >> 1);
    }

    auto stageA = [&](int tt) {
        u16* sA = &lds[(tt & 3) * 16384];
        const u16* g = Ab + (size_t)tt * 32;
        gload_lds16(g, sA + tid * 8);
        gload_lds16(g + rstride, sA + 4096 + tid * 8);
    };
    auto stageB = [&](int tt) {
        u16* sB = &lds[(tt & 3) * 16384 + 8192];
        const u16* g = Bb + (size_t)tt * 32;
        gload_lds16(g, sB + tid * 8);
        gload_lds16(g + rstride, sB + 4096 + tid * 8);
    };

    facc4 acc[8][4] = {};

    // prologue: stage tiles 0,1,2; confirm tile 0 (8 newest stay in flight)
    stageA(0); stageB(0);
    stageA(1); stageB(1);
    stageA(2); stageB(2);
    asm volatile("s_waitcnt vmcnt(8)" ::: "memory");
    __builtin_amdgcn_s_barrier();
    __builtin_amdgcn_sched_barrier(0);

    for (int t = 0; t < nt; ++t) {
        const u16* sA = &lds[(t & 3) * 16384];
        const u16* sB = sA + 8192;
        // ---- s0: B frags + A 0,1 ----
        frag8 b0[4], ap[2];
#pragma unroll
        for (int i = 0; i < 4; i++) b0[i] = *(const frag8*)&sB[boff[i]];
        ap[0] = *(const frag8*)&sA[aoff[0]];
        ap[1] = *(const frag8*)&sA[aoff[1]];
        if (t + 3 < nt) stageA(t + 3);
        __builtin_amdgcn_s_setprio(1);
#pragma unroll
        for (int m = 0; m < 2; m++)
#pragma unroll
            for (int nf = 0; nf < 4; nf++)
                acc[m][nf] = __builtin_amdgcn_mfma_f32_16x16x32_bf16(ap[m], b0[nf], acc[m][nf], 0, 0, 0);
        __builtin_amdgcn_s_setprio(0);
        // ---- s1: A 2,3 ----
        ap[0] = *(const frag8*)&sA[aoff[2]];
        ap[1] = *(const frag8*)&sA[aoff[3]];
        __builtin_amdgcn_s_setprio(1);
#pragma unroll
        for (int m = 0; m < 2; m++)
#pragma unroll
            for (int nf = 0; nf < 4; nf++)
                acc[2 + m][nf] = __builtin_amdgcn_mfma_f32_16x16x32_bf16(ap[m], b0[nf], acc[2 + m][nf], 0, 0, 0);
        __builtin_amdgcn_s_setprio(0);
        __builtin_amdgcn_s_barrier();  // mid-tile barrier
        // ---- s2: A 4,5 ----
        ap[0] = *(const frag8*)&sA[aoff[4]];
        ap[1] = *(const frag8*)&sA[aoff[5]];
        if (t + 3 < nt) stageB(t + 3);
        __builtin_amdgcn_s_setprio(1);
#pragma unroll
        for (int m = 0; m < 2; m++)
#pragma unroll
            for (int nf = 0; nf < 4; nf++)
                acc[4 + m][nf] = __builtin_amdgcn_mfma_f32_16x16x32_bf16(ap[m], b0[nf], acc[4 + m][nf], 0, 0, 0);
        __builtin_amdgcn_s_setprio(0);
        // ---- s3: A 6,7 ----
        ap[0] = *(const frag8*)&sA[aoff[6]];
        ap[1] = *(const frag8*)&sA[aoff[7]];
        __builtin_amdgcn_s_setprio(1);
#pragma unroll
        for (int m = 0; m < 2; m++)
#pragma unroll
            for (int nf = 0; nf < 4; nf++)
                acc[6 + m][nf] = __builtin_amdgcn_mfma_f32_16x16x32_bf16(ap[m], b0[nf], acc[6 + m][nf], 0, 0, 0);
        __builtin_amdgcn_s_setprio(0);
        // ---- tile boundary: derived wait ----
        if (t + 3 < nt)
            asm volatile("s_waitcnt vmcnt(8)" ::: "memory");
        else if (t + 2 < nt)
            asm volatile("s_waitcnt vmcnt(4)" ::: "memory");
        else
            asm volatile("s_waitcnt vmcnt(0)" ::: "memory");
        __builtin_amdgcn_s_barrier();
        __builtin_amdgcn_sched_barrier(0);
    }

    // ---- epilogue ----
    const int row0 = bm * 256 + wm * 128 + g4 * 4;
    const int col0 = bn * 256 + wn * 64 + l15;
    float* fout;
    if (EPI == 3) {
        const int z = blockIdx.z;
        fout = (z == 0) ? q0 : (z == 1) ? q1 : (z == 2) ? q2 : q3;
    } else {
        fout = (float*)Cout;
    }
#pragma unroll
    for (int nf = 0; nf < 4; nf++) {
        const int col = col0 + nf * 16;
        const float bv = (EPI == 3) ? 0.0f : bias[col];
#pragma unroll
        for (int mf = 0; mf < 8; mf++) {
#pragma unroll
            for (int r = 0; r < 4; r++) {
                const int row = row0 + mf * 16 + r;
                float v = acc[mf][nf][r] + bv;
                if (EPI == 2) v = gelu_exact(v);
                if (EPI == 0 || EPI == 3)
                    fout[(size_t)row * N + col] = v;
                else
                    ((u16*)Cout)[(size_t)row * N + col] = f2b(v);
            }
        }
    }
}

// ---------------- flash attention v7: 4 waves/block, 64 q-rows/block, KVBLK=64 ----------------
__global__ __launch_bounds__(256) void attn_kernel(const u16* __restrict__ qkv, u16* __restrict__ out) {
    __shared__ u16 kT[64 * 128];
    __shared__ u16 vT[128 * 64];
    const int h = blockIdx.y;
    // complementary pairing: co-resident blocks get qb summing to 31 (causal balance)
    const int qb = (blockIdx.y < 8) ? ((int)gridDim.x - 1 - (int)blockIdx.x) : (int)blockIdx.x;
    const int tid = threadIdx.x;
    const int lane = tid & 63, w = tid >> 6;
    const int l15 = lane & 15, g4 = lane >> 4;
    const int q0 = qb * 64 + w * 16;
    const float scale = 0.022097086912079608f;  // 1/sqrt(2048)

    frag8 qf[4];
    {
        const u16* qrow = qkv + (size_t)(q0 + l15) * N_QKV + h * HEAD_D + g4 * 8;
#pragma unroll
        for (int c = 0; c < 4; c++) qf[c] = *(const frag8*)(qrow + c * 32);
    }

    float m_run = -1e30f, l_run = 0.0f;
    facc4 o[8] = {};

    const int src0 = ((g4 & 1) << 5) + l15;
    const int src1 = src0 + 16;
    const bool hi = (g4 & 2) != 0;

    const int nt = qb + 1;
    for (int t = 0; t < nt; ++t) {
        const int kbase = t * 64;
        if (t) __syncthreads();
        const u16* kg_ptr = qkv + (size_t)kbase * N_QKV + D_MODEL + h * HEAD_D;
        const u16* vg_ptr = kg_ptr + D_MODEL;
        uint4 vv[4];
#pragma unroll
        for (int i = 0; i < 4; ++i)
            vv[i] = *(const uint4*)(vg_ptr + (size_t)lane * N_QKV + w * 32 + i * 8);
#pragma unroll
        for (int p = 0; p < 4; ++p) {
            const int c = p * 256 + tid;
            const int row = c >> 4;
            const int colb = (c & 15) << 4;
            const int srcb = colb ^ ((row & 7) << 4);
            gload_lds16(kg_ptr + (size_t)row * N_QKV + (srcb >> 1), &kT[c * 8]);
        }
        // V transpose-write, XOR-swizzled 16B chunks
#pragma unroll
        for (int i = 0; i < 4; ++i) {
            const u16* pv = (const u16*)&vv[i];
#pragma unroll
            for (int e = 0; e < 8; ++e) {
                const int d = w * 32 + i * 8 + e;
                vT[d * 64 + ((((lane >> 3) ^ (d & 7)) << 3) | (lane & 7))] = pv[e];
            }
        }
        __syncthreads();

        const bool last = (t == nt - 1);

        float st[16];
        float mx = -1e30f;
#pragma unroll
        for (int ks = 0; ks < 4; ++ks) {
            const bool active = !last || (ks <= w);
            if (active) {
                facc4 s = {};
                const int kl = ks * 16 + l15;
#pragma unroll
                for (int c = 0; c < 4; ++c) {
                    const int colb = (g4 * 16 + c * 64) ^ ((kl & 7) << 4);
                    frag8 kf = *(const frag8*)&kT[kl * 128 + (colb >> 1)];
                    s = __builtin_amdgcn_mfma_f32_16x16x32_bf16(kf, qf[c], s, 0, 0, 0);
                }
#pragma unroll
                for (int r = 0; r < 4; ++r) {
                    float v = s[r] * scale;
                    if (last) {
                        const int key = kbase + ks * 16 + g4 * 4 + r;
                        if (key > q0 + l15) v = -1e30f;
                    }
                    st[ks * 4 + r] = v;
                    mx = fmaxf(mx, v);
                }
            } else {
#pragma unroll
                for (int r = 0; r < 4; ++r) st[ks * 4 + r] = -1e30f;
            }
        }

        mx = fmaxf(mx, __shfl_xor(mx, 16));
        mx = fmaxf(mx, __shfl_xor(mx, 32));
        // T13 defer-max
        const bool skip = __all(mx <= m_run + 8.0f);
        const float m_new = skip ? m_run : fmaxf(m_run, mx);
        const float alpha = __expf(m_run - m_new);
        float ps = 0.0f;
        uint2 pb[4];
#pragma unroll
        for (int ks = 0; ks < 4; ++ks) {
            const float p0 = __expf(st[ks * 4 + 0] - m_new);
            const float p1 = __expf(st[ks * 4 + 1] - m_new);
            const float p2 = __expf(st[ks * 4 + 2] - m_new);
            const float p3 = __expf(st[ks * 4 + 3] - m_new);
            ps += (p0 + p1) + (p2 + p3);
            pb[ks].x = (unsigned)f2b(p0) | ((unsigned)f2b(p1) << 16);
            pb[ks].y = (unsigned)f2b(p2) | ((unsigned)f2b(p3) << 16);
        }
        ps += __shfl_xor(ps, 16);
        ps += __shfl_xor(ps, 32);
        l_run = l_run * alpha + ps;
        m_run = m_new;
        if (!skip) {
#pragma unroll
            for (int c8 = 0; c8 < 8; ++c8)
#pragma unroll
                for (int r = 0; r < 4; ++r) o[c8][r] *= alpha;
        }

#pragma unroll
        for (int kp = 0; kp < 2; ++kp) {
            const bool kp_active = !last || (kp == 0) || (w >= 2);
            if (kp_active) {
                const uint2 a = pb[2 * kp], b = pb[2 * kp + 1];
                const unsigned a0 = __shfl(a.x, src0), a1 = __shfl(a.y, src0);
                const unsigned a2 = __shfl(a.x, src1), a3 = __shfl(a.y, src1);
                const unsigned b0 = __shfl(b.x, src0), b1 = __shfl(b.y, src0);
                const unsigned b2 = __shfl(b.x, src1), b3 = __shfl(b.y, src1);
                union { unsigned u[4]; frag8 f; } pu;
                pu.u[0] = hi ? b0 : a0;
                pu.u[1] = hi ? b1 : a1;
                pu.u[2] = hi ? b2 : a2;
                pu.u[3] = hi ? b3 : a3;
                const frag8 pf = pu.f;
#pragma unroll
                for (int c8 = 0; c8 < 8; ++c8) {
                    const int d = c8 * 16 + l15;
                    const int ch = (((kp * 4 + g4) ^ (l15 & 7)) << 3);
                    frag8 vf = *(const frag8*)&vT[d * 64 + ch];
                    o[c8] = __builtin_amdgcn_mfma_f32_16x16x32_bf16(vf, pf, o[c8], 0, 0, 0);
                }
            }
        }
    }

    const float inv_l = 1.0f / l_run;
    u16* orow = out + (size_t)(q0 + l15) * D_MODEL + h * HEAD_D;
#pragma unroll
    for (int c8 = 0; c8 < 8; ++c8) {
        uint2 st2;
        st2.x = (unsigned)f2b(o[c8][0] * inv_l) | ((unsigned)f2b(o[c8][1] * inv_l) << 16);
        st2.y = (unsigned)f2b(o[c8][2] * inv_l) | ((unsigned)f2b(o[c8][3] * inv_l) << 16);
        *(uint2*)&orow[c8 * 16 + g4 * 4] = st2;
    }
}

// ---------------- residual + layernorm -> bf16 ----------------
__global__ __launch_bounds__(256) void ln_kernel(const float* __restrict__ a, const float* __restrict__ b,
                                                 const float* __restrict__ gamma, const float* __restrict__ beta,
                                                 u16* __restrict__ outb) {
    __shared__ float red[8];
    const int row = blockIdx.x;
    const int tid = threadIdx.x;
    const float* pa = a + (size_t)row * D_MODEL;
    const float* pb = b + (size_t)row * D_MODEL;
    float v[8];
    float s = 0.0f, s2 = 0.0f;
#pragma unroll
    for (int i = 0; i < 8; i++) {
        const int c = tid + i * 256;
        const float x = pa[c] + pb[c];
        v[i] = x;
        s += x;
        s2 += x * x;
    }
#pragma unroll
    for (int off = 32; off; off >>= 1) {
        s += __shfl_xor(s, off);
        s2 += __shfl_xor(s2, off);
    }
    if ((tid & 63) == 0) { red[(tid >> 6) * 2] = s; red[(tid >> 6) * 2 + 1] = s2; }
    __syncthreads();
    s = red[0] + red[2] + red[4] + red[6];
    s2 = red[1] + red[3] + red[5] + red[7];
    const float mean = s * (1.0f / D_MODEL);
    const float var = s2 * (1.0f / D_MODEL) - mean * mean;
    const float rstd = rsqrtf(var + 1e-5f);
#pragma unroll
    for (int i = 0; i < 8; i++) {
        const int c = tid + i * 256;
        outb[(size_t)row * D_MODEL + c] = f2b((v[i] - mean) * rstd * gamma[c] + beta[c]);
    }
}

// ---------------- bf16 residual + Σ split-K partials + bias + layernorm -> f32 ----------------
__global__ __launch_bounds__(256) void ln_part_kernel(const u16* __restrict__ hb,
                                                      const float* __restrict__ p0, const float* __restrict__ p1,
                                                      const float* __restrict__ p2, const float* __restrict__ p3,
                                                      int np, const float* __restrict__ bias,
                                                      const float* __restrict__ gamma, const float* __restrict__ beta,
                                                      float* __restrict__ outf) {
    __shared__ float red[8];
    const int row = blockIdx.x;
    const int tid = threadIdx.x;
    const size_t rb = (size_t)row * D_MODEL;
    float v[8];
    float s = 0.0f, s2 = 0.0f;
#pragma unroll
    for (int i = 0; i < 8; i++) {
        const int c = tid + i * 256;
        float x = b2f(hb[rb + c]) + bias[c] + p0[rb + c] + p1[rb + c];
        if (np > 2) x += p2[rb + c];
        if (np > 3) x += p3[rb + c];
        v[i] = x;
        s += x;
        s2 += x * x;
    }
#pragma unroll
    for (int off = 32; off; off >>= 1) {
        s += __shfl_xor(s, off);
        s2 += __shfl_xor(s2, off);
    }
    if ((tid & 63) == 0) { red[(tid >> 6) * 2] = s; red[(tid >> 6) * 2 + 1] = s2; }
    __syncthreads();
    s = red[0] + red[2] + red[4] + red[6];
    s2 = red[1] + red[3] + red[5] + red[7];
    const float mean = s * (1.0f / D_MODEL);
    const float var = s2 * (1.0f / D_MODEL) - mean * mean;
    const float rstd = rsqrtf(var + 1e-5f);
#pragma unroll
    for (int i = 0; i < 8; i++) {
        const int c = tid + i * 256;
        outf[rb + c] = (v[i] - mean) * rstd * gamma[c] + beta[c];
    }
}

extern "C" void kernel_launch(void* const* d_in, const int* in_sizes, int n_in,
                              void* d_out, int out_size, void* d_ws, size_t ws_size,
                              hipStream_t stream) {
    const float* x    = (const float*)d_in[0];
    const float* Wqkv = (const float*)d_in[1];
    const float* bqkv = (const float*)d_in[2];
    const float* Wo   = (const float*)d_in[3];
    const float* bo   = (const float*)d_in[4];
    const float* W1   = (const float*)d_in[5];
    const float* b1   = (const float*)d_in[6];
    const float* W2   = (const float*)d_in[7];
    const float* b2   = (const float*)d_in[8];
    const float* g1   = (const float*)d_in[9];
    const float* be1  = (const float*)d_in[10];
    const float* g2   = (const float*)d_in[11];
    const float* be2  = (const float*)d_in[12];

    char* ws = (char*)d_ws;
    const size_t MB = 1024 * 1024;
    // layout (stream-ordered reuse; peak 120 MB, 136 MB if available):
    u16*  xb     = (u16*)(ws + 0);          // [0,8)
    u16*  WqkvT  = (u16*)(ws + 8 * MB);     // [8,32)
    u16*  qkv    = (u16*)(ws + 32 * MB);    // [32,56)
    u16*  attn_o = (u16*)(ws + 56 * MB);    // [56,64)
    u16*  WoT    = (u16*)(ws + 8 * MB);     // [8,16)   reuses WqkvT (dead)
    float* proj  = (float*)(ws + 16 * MB);  // [16,32)
    u16*  hb     = (u16*)(ws + 0);          // [0,8)    reuses xb (dead)
    u16*  W1T    = (u16*)(ws + 8 * MB);     // [8,40)   reuses WoT+proj (dead)
    u16*  f1     = (u16*)(ws + 40 * MB);    // [40,72)
    u16*  W2T    = (u16*)(ws + 72 * MB);    // [72,104)
    float* part0 = (float*)(ws + 8 * MB);   // [8,24)   reuses W1T (dead)
    float* part1 = (float*)(ws + 24 * MB);  // [24,40)
    float* part2 = (float*)(ws + 104 * MB); // [104,120)
    float* part3 = (float*)(ws + 120 * MB); // [120,136) only if ws >= 136 MB

    const int np = (ws_size >= 136 * MB) ? 4 : 3;
    const int kseg = (np == 4) ? 2048 : 2688;  // last z-plane takes remainder

    // 1. x -> bf16
    cvt_bf16_kernel<<<2048, 256, 0, stream>>>(x, xb, L_SEQ * D_MODEL);
    // 2. Wqkv^T
    tr_cvt64<<<dim3(N_QKV / 64, D_MODEL / 64), 256, 0, stream>>>(Wqkv, WqkvT, D_MODEL, N_QKV);
    // 3. qkv = x @ Wqkv + bqkv (bf16), grid 192
    gemm256<1><<<dim3(192, 1, 1), 512, 0, stream>>>(xb, WqkvT, bqkv, qkv, nullptr, nullptr, nullptr, nullptr,
                                                    L_SEQ, N_QKV, D_MODEL, D_MODEL, 8);
    // 4. attention
    attn_kernel<<<dim3(L_SEQ / 64, N_HEADS), 256, 0, stream>>>(qkv, attn_o);
    // 5. Wo^T
    tr_cvt64<<<dim3(D_MODEL / 64, D_MODEL / 64), 256, 0, stream>>>(Wo, WoT, D_MODEL, D_MODEL);
    // 6. proj = attn @ Wo + bo (f32)
    gemm_bt<<<dim3(D_MODEL / 128, L_SEQ / 128), 256, 0, stream>>>(attn_o, WoT, bo, proj, L_SEQ, D_MODEL, D_MODEL);
    // 7. hb = bf16(LN(x + proj))
    ln_kernel<<<L_SEQ, 256, 0, stream>>>(x, proj, g1, be1, hb);
    // 8. W1^T
    tr_cvt64<<<dim3(D_INNER / 64, D_MODEL / 64), 256, 0, stream>>>(W1, W1T, D_MODEL, D_INNER);
    // 9. f1 = gelu(hb @ W1 + b1) (bf16), grid 256
    gemm256<2><<<dim3(256, 1, 1), 512, 0, stream>>>(hb, W1T, b1, f1, nullptr, nullptr, nullptr, nullptr,
                                                    L_SEQ, D_INNER, D_MODEL, D_MODEL, 8);
    // 10. W2^T
    tr_cvt64<<<dim3(D_MODEL / 64, D_INNER / 64), 256, 0, stream>>>(W2, W2T, D_INNER, D_MODEL);
    // 11. f2 partials = f1 @ W2 (split-K=np, f32 planes)
    gemm256<3><<<dim3(64, 1, np), 512, 0, stream>>>(f1, W2T, nullptr, nullptr, part0, part1, part2, part3,
                                                    L_SEQ, D_MODEL, D_INNER, kseg, 8);
    // 12. out = LN(hb + Σparts + b2)*g2+be2
    ln_part_kernel<<<L_SEQ, 256, 0, stream>>>(hb, part0, part1, part2, part3, np, b2, g2, be2, (float*)d_out);
}

// Round 9
// 466.306 us; speedup vs baseline: 4.4206x; 1.0127x over previous
//
#include <hip/hip_runtime.h>
#include <hip/hip_bf16.h>

typedef unsigned short u16;
typedef __attribute__((ext_vector_type(8))) short frag8;   // 8 bf16
typedef __attribute__((ext_vector_type(4))) float facc4;   // 4 f32

#define L_SEQ 2048
#define D_MODEL 2048
#define N_HEADS 16
#define HEAD_D 128
#define N_QKV 6144
#define D_INNER 8192

__device__ __forceinline__ u16 f2b(float f) {
    __hip_bfloat16 h = __float2bfloat16(f);
    return *reinterpret_cast<u16*>(&h);
}

__device__ __forceinline__ float b2f(u16 u) {
    __hip_bfloat16 h = *reinterpret_cast<__hip_bfloat16*>(&u);
    return __bfloat162float(h);
}

__device__ __forceinline__ void gload_lds16(const void* g, void* l) {
    __builtin_amdgcn_global_load_lds(
        (const __attribute__((address_space(1))) unsigned int*)g,
        (__attribute__((address_space(3))) unsigned int*)l, 16, 0, 0);
}

__device__ __forceinline__ float gelu_exact(float x) {
    return 0.5f * x * (1.0f + erff(x * 0.7071067811865475f));
}

// ---------------- elementwise f32 -> bf16 (vectorized) ----------------
__global__ __launch_bounds__(256) void cvt_bf16_kernel(const float* __restrict__ in, u16* __restrict__ out, int n) {
    const int i = (blockIdx.x * 256 + threadIdx.x) * 8;
    if (i >= n) return;
    float4 a = *(const float4*)(in + i);
    float4 b = *(const float4*)(in + i + 4);
    u16 tmp[8];
    tmp[0] = f2b(a.x); tmp[1] = f2b(a.y); tmp[2] = f2b(a.z); tmp[3] = f2b(a.w);
    tmp[4] = f2b(b.x); tmp[5] = f2b(b.y); tmp[6] = f2b(b.z); tmp[7] = f2b(b.w);
    *(uint4*)(out + i) = *(uint4*)tmp;
}

// ---------------- transpose + convert: f32 [R][C] -> bf16 [C][R], 64x64 tiles ----------------
__global__ __launch_bounds__(256) void tr_cvt64(const float* __restrict__ in, u16* __restrict__ out, int R, int C) {
    __shared__ float t[64][68];
    const int bx = blockIdx.x * 64;  // C dim
    const int by = blockIdx.y * 64;  // R dim
    const int tid = threadIdx.x;
    {
        const int r = tid >> 2;
        const int c4 = (tid & 3) * 16;
        const float* src = in + (size_t)(by + r) * C + bx + c4;
#pragma unroll
        for (int j = 0; j < 4; ++j)
            *(float4*)&t[r][c4 + 4 * j] = *(const float4*)(src + 4 * j);
    }
    __syncthreads();
    {
        const int cc = tid >> 2;
        const int rr0 = (tid & 3) * 16;
        u16 tmp[16];
#pragma unroll
        for (int j = 0; j < 16; ++j) tmp[j] = f2b(t[rr0 + j][cc]);
        u16* dst = out + (size_t)(bx + cc) * R + by + rr0;
        *(uint4*)(dst) = *(uint4*)&tmp[0];
        *(uint4*)(dst + 8) = *(uint4*)&tmp[8];
    }
}

// ---------------- legacy 128x128 GEMM (proj) ----------------
__global__ __launch_bounds__(256) void gemm_bt(const u16* __restrict__ A, const u16* __restrict__ Bt,
                                               const float* __restrict__ bias, float* __restrict__ Cout,
                                               int M, int N, int K) {
    __shared__ u16 lA[128 * 64];
    __shared__ u16 lB[128 * 64];
    const int tid = threadIdx.x;
    const int lane = tid & 63, wid = tid >> 6;
    const int wr = wid >> 1, wc = wid & 1;
    const int l15 = lane & 15, g4 = lane >> 4;
    const int bm = blockIdx.y, bn = blockIdx.x;

    const int arow = tid >> 3;
    const int acol = (tid & 7) * 8;
    const size_t abase = (size_t)(bm * 128) * K + acol;
    const size_t bbase = (size_t)(bn * 128) * K + acol;

    facc4 acc[4][4] = {};

    for (int k0 = 0; k0 < K; k0 += 64) {
        if (k0) __syncthreads();
#pragma unroll
        for (int i = 0; i < 4; i++) {
            gload_lds16(A + abase + (size_t)(i * 32 + arow) * K + k0, &lA[i * 2048 + tid * 8]);
            gload_lds16(Bt + bbase + (size_t)(i * 32 + arow) * K + k0, &lB[i * 2048 + tid * 8]);
        }
        __syncthreads();
#pragma unroll
        for (int kk = 0; kk < 64; kk += 32) {
            frag8 af[4], bf[4];
#pragma unroll
            for (int m = 0; m < 4; m++)
                af[m] = *(const frag8*)&lA[(wr * 64 + m * 16 + l15) * 64 + kk + g4 * 8];
#pragma unroll
            for (int n = 0; n < 4; n++)
                bf[n] = *(const frag8*)&lB[(wc * 64 + n * 16 + l15) * 64 + kk + g4 * 8];
#pragma unroll
            for (int m = 0; m < 4; m++)
#pragma unroll
                for (int n = 0; n < 4; n++)
                    acc[m][n] = __builtin_amdgcn_mfma_f32_16x16x32_bf16(af[m], bf[n], acc[m][n], 0, 0, 0);
        }
    }

    const int row0 = bm * 128 + wr * 64 + g4 * 4;
    const int col0 = bn * 128 + wc * 64 + l15;
#pragma unroll
    for (int n = 0; n < 4; n++) {
        const int col = col0 + n * 16;
        const float bv = bias[col];
#pragma unroll
        for (int m = 0; m < 4; m++)
#pragma unroll
            for (int r = 0; r < 4; r++)
                Cout[(size_t)(row0 + m * 16 + r) * N + col] = acc[m][n][r] + bv;
    }
}

// ---------------- gemm256 v9: 256x256, BK=32, ring-4, 4-sub-phase read-ahead schedule ----------------
// Round-8 staging skeleton (slots, issue points, vmcnt(8) derivation, T2 swizzle) unchanged.
// v9: frag reads lead their MFMA by one sub-phase; each sub-phase = {reads, stage} -> barrier ->
// MFMA, so read latency is absorbed by the barrier wait (m196/m218 mechanism, counted vmcnt kept).
template <int EPI>
__global__ __launch_bounds__(512, 2) void gemm256(const u16* __restrict__ A, const u16* __restrict__ Bt,
                                                  const float* __restrict__ bias, void* __restrict__ Cout,
                                                  float* __restrict__ q0, float* __restrict__ q1,
                                                  float* __restrict__ q2, float* __restrict__ q3,
                                                  int M, int N, int K, int kseg, int nbm) {
    __shared__ u16 lds[4 * 16384];  // slot s: A at s*16384, B at s*16384+8192 (u16 units)
    const int tid = threadIdx.x;
    const int lane = tid & 63, wid = tid >> 6;
    const int wm = wid >> 2, wn = wid & 3;
    const int l15 = lane & 15, g4 = lane >> 4;

    const int nwg = gridDim.x;
    const int q8 = nwg >> 3;
    const int wg = (blockIdx.x & 7) * q8 + (blockIdx.x >> 3);
    const int bm = wg % nbm, bn = wg / nbm;
    const int kb = blockIdx.z * kseg;
    const int ksz = (blockIdx.z == (int)gridDim.z - 1) ? (K - kb) : kseg;
    const int nt = ksz >> 5;

    const int rA = tid >> 2;
    const int swzT = ((tid >> 3) & 3) << 4;
    const int srcE = ((((tid & 3) << 4) ^ swzT) >> 1);
    const u16* Ab = A + (size_t)(bm * 256 + rA) * K + kb + srcE;
    const u16* Bb = Bt + (size_t)(bn * 256 + rA) * K + kb + srcE;
    const size_t rstride = (size_t)128 * K;

    int aoff[8], boff[4];
#pragma unroll
    for (int mf = 0; mf < 8; mf++) {
        const int rowl = wm * 128 + mf * 16 + l15;
        aoff[mf] = rowl * 32 + (((g4 * 16) ^ (((rowl >> 1) & 3) << 4)) >> 1);
    }
#pragma unroll
    for (int nf = 0; nf < 4; nf++) {
        const int rowl = wn * 64 + nf * 16 + l15;
        boff[nf] = rowl * 32 + (((g4 * 16) ^ (((rowl >> 1) & 3) << 4)) >> 1);
    }

    auto stageA = [&](int tt) {
        u16* sA = &lds[(tt & 3) * 16384];
        const u16* g = Ab + (size_t)tt * 32;
        gload_lds16(g, sA + tid * 8);
        gload_lds16(g + rstride, sA + 4096 + tid * 8);
    };
    auto stageB = [&](int tt) {
        u16* sB = &lds[(tt & 3) * 16384 + 8192];
        const u16* g = Bb + (size_t)tt * 32;
        gload_lds16(g, sB + tid * 8);
        gload_lds16(g + rstride, sB + 4096 + tid * 8);
    };

    facc4 acc[8][4] = {};

    // prologue: stage tiles 0,1,2; confirm tile 0 (8 newest stay in flight)
    stageA(0); stageB(0);
    stageA(1); stageB(1);
    stageA(2); stageB(2);
    asm volatile("s_waitcnt vmcnt(8)" ::: "memory");
    __builtin_amdgcn_s_barrier();
    __builtin_amdgcn_sched_barrier(0);

    // pre-read tile 0's B and A0,A1
    frag8 bc[4], bn_[4];
    frag8 ca0, ca1, ra0, ra1, rb0, rb1, rc0, rc1, na0, na1;
    {
        const u16* sA = &lds[0];
        const u16* sB = sA + 8192;
#pragma unroll
        for (int i = 0; i < 4; i++) bc[i] = *(const frag8*)&sB[boff[i]];
        ca0 = *(const frag8*)&sA[aoff[0]];
        ca1 = *(const frag8*)&sA[aoff[1]];
    }

    for (int t = 0; t < nt; ++t) {
        const u16* sA = &lds[(t & 3) * 16384];
        // ---- s0: read A2,A3 | barrier | MFMA (A0,A1) ----
        ra0 = *(const frag8*)&sA[aoff[2]];
        ra1 = *(const frag8*)&sA[aoff[3]];
        __builtin_amdgcn_sched_barrier(0);
        __builtin_amdgcn_s_barrier();
        __builtin_amdgcn_sched_barrier(0);
        __builtin_amdgcn_s_setprio(1);
#pragma unroll
        for (int nf = 0; nf < 4; nf++) {
            acc[0][nf] = __builtin_amdgcn_mfma_f32_16x16x32_bf16(ca0, bc[nf], acc[0][nf], 0, 0, 0);
            acc[1][nf] = __builtin_amdgcn_mfma_f32_16x16x32_bf16(ca1, bc[nf], acc[1][nf], 0, 0, 0);
        }
        __builtin_amdgcn_s_setprio(0);
        // ---- s1: read A4,A5 + stageA(t+3) | barrier | MFMA (A2,A3) ----
        rb0 = *(const frag8*)&sA[aoff[4]];
        rb1 = *(const frag8*)&sA[aoff[5]];
        if (t + 3 < nt) stageA(t + 3);
        __builtin_amdgcn_sched_barrier(0);
        __builtin_amdgcn_s_barrier();
        __builtin_amdgcn_sched_barrier(0);
        __builtin_amdgcn_s_setprio(1);
#pragma unroll
        for (int nf = 0; nf < 4; nf++) {
            acc[2][nf] = __builtin_amdgcn_mfma_f32_16x16x32_bf16(ra0, bc[nf], acc[2][nf], 0, 0, 0);
            acc[3][nf] = __builtin_amdgcn_mfma_f32_16x16x32_bf16(ra1, bc[nf], acc[3][nf], 0, 0, 0);
        }
        __builtin_amdgcn_s_setprio(0);
        // ---- s2: read A6,A7 + stageB(t+3) | barrier | MFMA (A4,A5) ----
        rc0 = *(const frag8*)&sA[aoff[6]];
        rc1 = *(const frag8*)&sA[aoff[7]];
        if (t + 3 < nt) stageB(t + 3);
        __builtin_amdgcn_sched_barrier(0);
        __builtin_amdgcn_s_barrier();
        __builtin_amdgcn_sched_barrier(0);
        __builtin_amdgcn_s_setprio(1);
#pragma unroll
        for (int nf = 0; nf < 4; nf++) {
            acc[4][nf] = __builtin_amdgcn_mfma_f32_16x16x32_bf16(rb0, bc[nf], acc[4][nf], 0, 0, 0);
            acc[5][nf] = __builtin_amdgcn_mfma_f32_16x16x32_bf16(rb1, bc[nf], acc[5][nf], 0, 0, 0);
        }
        __builtin_amdgcn_s_setprio(0);
        // ---- s3: derived wait + barrier | read next tile's B,A0,A1 | MFMA (A6,A7) ----
        if (t + 3 < nt)
            asm volatile("s_waitcnt vmcnt(8)" ::: "memory");
        else if (t + 2 < nt)
            asm volatile("s_waitcnt vmcnt(4)" ::: "memory");
        else
            asm volatile("s_waitcnt vmcnt(0)" ::: "memory");
        __builtin_amdgcn_s_barrier();
        __builtin_amdgcn_sched_barrier(0);
        if (t + 1 < nt) {
            const u16* nA = &lds[((t + 1) & 3) * 16384];
            const u16* nB = nA + 8192;
#pragma unroll
            for (int i = 0; i < 4; i++) bn_[i] = *(const frag8*)&nB[boff[i]];
            na0 = *(const frag8*)&nA[aoff[0]];
            na1 = *(const frag8*)&nA[aoff[1]];
        }
        __builtin_amdgcn_s_setprio(1);
#pragma unroll
        for (int nf = 0; nf < 4; nf++) {
            acc[6][nf] = __builtin_amdgcn_mfma_f32_16x16x32_bf16(rc0, bc[nf], acc[6][nf], 0, 0, 0);
            acc[7][nf] = __builtin_amdgcn_mfma_f32_16x16x32_bf16(rc1, bc[nf], acc[7][nf], 0, 0, 0);
        }
        __builtin_amdgcn_s_setprio(0);
        if (t + 1 < nt) {
#pragma unroll
            for (int i = 0; i < 4; i++) bc[i] = bn_[i];
            ca0 = na0;
            ca1 = na1;
        }
    }

    // ---- epilogue ----
    const int row0 = bm * 256 + wm * 128 + g4 * 4;
    const int col0 = bn * 256 + wn * 64 + l15;
    float* fout;
    if (EPI == 3) {
        const int z = blockIdx.z;
        fout = (z == 0) ? q0 : (z == 1) ? q1 : (z == 2) ? q2 : q3;
    } else {
        fout = (float*)Cout;
    }
#pragma unroll
    for (int nf = 0; nf < 4; nf++) {
        const int col = col0 + nf * 16;
        const float bv = (EPI == 3) ? 0.0f : bias[col];
#pragma unroll
        for (int mf = 0; mf < 8; mf++) {
#pragma unroll
            for (int r = 0; r < 4; r++) {
                const int row = row0 + mf * 16 + r;
                float v = acc[mf][nf][r] + bv;
                if (EPI == 2) v = gelu_exact(v);
                if (EPI == 0 || EPI == 3)
                    fout[(size_t)row * N + col] = v;
                else
                    ((u16*)Cout)[(size_t)row * N + col] = f2b(v);
            }
        }
    }
}

// ---------------- flash attention v7 (unchanged) ----------------
__global__ __launch_bounds__(256) void attn_kernel(const u16* __restrict__ qkv, u16* __restrict__ out) {
    __shared__ u16 kT[64 * 128];
    __shared__ u16 vT[128 * 64];
    const int h = blockIdx.y;
    const int qb = (blockIdx.y < 8) ? ((int)gridDim.x - 1 - (int)blockIdx.x) : (int)blockIdx.x;
    const int tid = threadIdx.x;
    const int lane = tid & 63, w = tid >> 6;
    const int l15 = lane & 15, g4 = lane >> 4;
    const int q0 = qb * 64 + w * 16;
    const float scale = 0.022097086912079608f;

    frag8 qf[4];
    {
        const u16* qrow = qkv + (size_t)(q0 + l15) * N_QKV + h * HEAD_D + g4 * 8;
#pragma unroll
        for (int c = 0; c < 4; c++) qf[c] = *(const frag8*)(qrow + c * 32);
    }

    float m_run = -1e30f, l_run = 0.0f;
    facc4 o[8] = {};

    const int src0 = ((g4 & 1) << 5) + l15;
    const int src1 = src0 + 16;
    const bool hi = (g4 & 2) != 0;

    const int nt = qb + 1;
    for (int t = 0; t < nt; ++t) {
        const int kbase = t * 64;
        if (t) __syncthreads();
        const u16* kg_ptr = qkv + (size_t)kbase * N_QKV + D_MODEL + h * HEAD_D;
        const u16* vg_ptr = kg_ptr + D_MODEL;
        uint4 vv[4];
#pragma unroll
        for (int i = 0; i < 4; ++i)
            vv[i] = *(const uint4*)(vg_ptr + (size_t)lane * N_QKV + w * 32 + i * 8);
#pragma unroll
        for (int p = 0; p < 4; ++p) {
            const int c = p * 256 + tid;
            const int row = c >> 4;
            const int colb = (c & 15) << 4;
            const int srcb = colb ^ ((row & 7) << 4);
            gload_lds16(kg_ptr + (size_t)row * N_QKV + (srcb >> 1), &kT[c * 8]);
        }
#pragma unroll
        for (int i = 0; i < 4; ++i) {
            const u16* pv = (const u16*)&vv[i];
#pragma unroll
            for (int e = 0; e < 8; ++e) {
                const int d = w * 32 + i * 8 + e;
                vT[d * 64 + ((((lane >> 3) ^ (d & 7)) << 3) | (lane & 7))] = pv[e];
            }
        }
        __syncthreads();

        const bool last = (t == nt - 1);

        float st[16];
        float mx = -1e30f;
#pragma unroll
        for (int ks = 0; ks < 4; ++ks) {
            const bool active = !last || (ks <= w);
            if (active) {
                facc4 s = {};
                const int kl = ks * 16 + l15;
#pragma unroll
                for (int c = 0; c < 4; ++c) {
                    const int colb = (g4 * 16 + c * 64) ^ ((kl & 7) << 4);
                    frag8 kf = *(const frag8*)&kT[kl * 128 + (colb >> 1)];
                    s = __builtin_amdgcn_mfma_f32_16x16x32_bf16(kf, qf[c], s, 0, 0, 0);
                }
#pragma unroll
                for (int r = 0; r < 4; ++r) {
                    float v = s[r] * scale;
                    if (last) {
                        const int key = kbase + ks * 16 + g4 * 4 + r;
                        if (key > q0 + l15) v = -1e30f;
                    }
                    st[ks * 4 + r] = v;
                    mx = fmaxf(mx, v);
                }
            } else {
#pragma unroll
                for (int r = 0; r < 4; ++r) st[ks * 4 + r] = -1e30f;
            }
        }

        mx = fmaxf(mx, __shfl_xor(mx, 16));
        mx = fmaxf(mx, __shfl_xor(mx, 32));
        const bool skip = __all(mx <= m_run + 8.0f);
        const float m_new = skip ? m_run : fmaxf(m_run, mx);
        const float alpha = __expf(m_run - m_new);
        float ps = 0.0f;
        uint2 pb[4];
#pragma unroll
        for (int ks = 0; ks < 4; ++ks) {
            const float p0 = __expf(st[ks * 4 + 0] - m_new);
            const float p1 = __expf(st[ks * 4 + 1] - m_new);
            const float p2 = __expf(st[ks * 4 + 2] - m_new);
            const float p3 = __expf(st[ks * 4 + 3] - m_new);
            ps += (p0 + p1) + (p2 + p3);
            pb[ks].x = (unsigned)f2b(p0) | ((unsigned)f2b(p1) << 16);
            pb[ks].y = (unsigned)f2b(p2) | ((unsigned)f2b(p3) << 16);
        }
        ps += __shfl_xor(ps, 16);
        ps += __shfl_xor(ps, 32);
        l_run = l_run * alpha + ps;
        m_run = m_new;
        if (!skip) {
#pragma unroll
            for (int c8 = 0; c8 < 8; ++c8)
#pragma unroll
                for (int r = 0; r < 4; ++r) o[c8][r] *= alpha;
        }

#pragma unroll
        for (int kp = 0; kp < 2; ++kp) {
            const bool kp_active = !last || (kp == 0) || (w >= 2);
            if (kp_active) {
                const uint2 a = pb[2 * kp], b = pb[2 * kp + 1];
                const unsigned a0 = __shfl(a.x, src0), a1 = __shfl(a.y, src0);
                const unsigned a2 = __shfl(a.x, src1), a3 = __shfl(a.y, src1);
                const unsigned b0 = __shfl(b.x, src0), b1 = __shfl(b.y, src0);
                const unsigned b2 = __shfl(b.x, src1), b3 = __shfl(b.y, src1);
                union { unsigned u[4]; frag8 f; } pu;
                pu.u[0] = hi ? b0 : a0;
                pu.u[1] = hi ? b1 : a1;
                pu.u[2] = hi ? b2 : a2;
                pu.u[3] = hi ? b3 : a3;
                const frag8 pf = pu.f;
#pragma unroll
                for (int c8 = 0; c8 < 8; ++c8) {
                    const int d = c8 * 16 + l15;
                    const int ch = (((kp * 4 + g4) ^ (l15 & 7)) << 3);
                    frag8 vf = *(const frag8*)&vT[d * 64 + ch];
                    o[c8] = __builtin_amdgcn_mfma_f32_16x16x32_bf16(vf, pf, o[c8], 0, 0, 0);
                }
            }
        }
    }

    const float inv_l = 1.0f / l_run;
    u16* orow = out + (size_t)(q0 + l15) * D_MODEL + h * HEAD_D;
#pragma unroll
    for (int c8 = 0; c8 < 8; ++c8) {
        uint2 st2;
        st2.x = (unsigned)f2b(o[c8][0] * inv_l) | ((unsigned)f2b(o[c8][1] * inv_l) << 16);
        st2.y = (unsigned)f2b(o[c8][2] * inv_l) | ((unsigned)f2b(o[c8][3] * inv_l) << 16);
        *(uint2*)&orow[c8 * 16 + g4 * 4] = st2;
    }
}

// ---------------- residual + layernorm -> bf16 ----------------
__global__ __launch_bounds__(256) void ln_kernel(const float* __restrict__ a, const float* __restrict__ b,
                                                 const float* __restrict__ gamma, const float* __restrict__ beta,
                                                 u16* __restrict__ outb) {
    __shared__ float red[8];
    const int row = blockIdx.x;
    const int tid = threadIdx.x;
    const float* pa = a + (size_t)row * D_MODEL;
    const float* pb = b + (size_t)row * D_MODEL;
    float v[8];
    float s = 0.0f, s2 = 0.0f;
#pragma unroll
    for (int i = 0; i < 8; i++) {
        const int c = tid + i * 256;
        const float x = pa[c] + pb[c];
        v[i] = x;
        s += x;
        s2 += x * x;
    }
#pragma unroll
    for (int off = 32; off; off >>= 1) {
        s += __shfl_xor(s, off);
        s2 += __shfl_xor(s2, off);
    }
    if ((tid & 63) == 0) { red[(tid >> 6) * 2] = s; red[(tid >> 6) * 2 + 1] = s2; }
    __syncthreads();
    s = red[0] + red[2] + red[4] + red[6];
    s2 = red[1] + red[3] + red[5] + red[7];
    const float mean = s * (1.0f / D_MODEL);
    const float var = s2 * (1.0f / D_MODEL) - mean * mean;
    const float rstd = rsqrtf(var + 1e-5f);
#pragma unroll
    for (int i = 0; i < 8; i++) {
        const int c = tid + i * 256;
        outb[(size_t)row * D_MODEL + c] = f2b((v[i] - mean) * rstd * gamma[c] + beta[c]);
    }
}

// ---------------- bf16 residual + Σ split-K partials + bias + layernorm -> f32 ----------------
__global__ __launch_bounds__(256) void ln_part_kernel(const u16* __restrict__ hb,
                                                      const float* __restrict__ p0, const float* __restrict__ p1,
                                                      const float* __restrict__ p2, const float* __restrict__ p3,
                                                      int np, const float* __restrict__ bias,
                                                      const float* __restrict__ gamma, const float* __restrict__ beta,
                                                      float* __restrict__ outf) {
    __shared__ float red[8];
    const int row = blockIdx.x;
    const int tid = threadIdx.x;
    const size_t rb = (size_t)row * D_MODEL;
    float v[8];
    float s = 0.0f, s2 = 0.0f;
#pragma unroll
    for (int i = 0; i < 8; i++) {
        const int c = tid + i * 256;
        float x = b2f(hb[rb + c]) + bias[c] + p0[rb + c] + p1[rb + c];
        if (np > 2) x += p2[rb + c];
        if (np > 3) x += p3[rb + c];
        v[i] = x;
        s += x;
        s2 += x * x;
    }
#pragma unroll
    for (int off = 32; off; off >>= 1) {
        s += __shfl_xor(s, off);
        s2 += __shfl_xor(s2, off);
    }
    if ((tid & 63) == 0) { red[(tid >> 6) * 2] = s; red[(tid >> 6) * 2 + 1] = s2; }
    __syncthreads();
    s = red[0] + red[2] + red[4] + red[6];
    s2 = red[1] + red[3] + red[5] + red[7];
    const float mean = s * (1.0f / D_MODEL);
    const float var = s2 * (1.0f / D_MODEL) - mean * mean;
    const float rstd = rsqrtf(var + 1e-5f);
#pragma unroll
    for (int i = 0; i < 8; i++) {
        const int c = tid + i * 256;
        outf[rb + c] = (v[i] - mean) * rstd * gamma[c] + beta[c];
    }
}

extern "C" void kernel_launch(void* const* d_in, const int* in_sizes, int n_in,
                              void* d_out, int out_size, void* d_ws, size_t ws_size,
                              hipStream_t stream) {
    const float* x    = (const float*)d_in[0];
    const float* Wqkv = (const float*)d_in[1];
    const float* bqkv = (const float*)d_in[2];
    const float* Wo   = (const float*)d_in[3];
    const float* bo   = (const float*)d_in[4];
    const float* W1   = (const float*)d_in[5];
    const float* b1   = (const float*)d_in[6];
    const float* W2   = (const float*)d_in[7];
    const float* b2   = (const float*)d_in[8];
    const float* g1   = (const float*)d_in[9];
    const float* be1  = (const float*)d_in[10];
    const float* g2   = (const float*)d_in[11];
    const float* be2  = (const float*)d_in[12];

    char* ws = (char*)d_ws;
    const size_t MB = 1024 * 1024;
    u16*  xb     = (u16*)(ws + 0);          // [0,8)
    u16*  WqkvT  = (u16*)(ws + 8 * MB);     // [8,32)
    u16*  qkv    = (u16*)(ws + 32 * MB);    // [32,56)
    u16*  attn_o = (u16*)(ws + 56 * MB);    // [56,64)
    u16*  WoT    = (u16*)(ws + 8 * MB);     // [8,16)   reuses WqkvT (dead)
    float* proj  = (float*)(ws + 16 * MB);  // [16,32)
    u16*  hb     = (u16*)(ws + 0);          // [0,8)    reuses xb (dead)
    u16*  W1T    = (u16*)(ws + 8 * MB);     // [8,40)   reuses WoT+proj (dead)
    u16*  f1     = (u16*)(ws + 40 * MB);    // [40,72)
    u16*  W2T    = (u16*)(ws + 72 * MB);    // [72,104)
    float* part0 = (float*)(ws + 8 * MB);   // [8,24)   reuses W1T (dead)
    float* part1 = (float*)(ws + 24 * MB);  // [24,40)
    float* part2 = (float*)(ws + 104 * MB); // [104,120)
    float* part3 = (float*)(ws + 120 * MB); // [120,136) only if ws >= 136 MB

    const int np = (ws_size >= 136 * MB) ? 4 : 3;
    const int kseg = (np == 4) ? 2048 : 2688;

    // 1. x -> bf16
    cvt_bf16_kernel<<<2048, 256, 0, stream>>>(x, xb, L_SEQ * D_MODEL);
    // 2. Wqkv^T
    tr_cvt64<<<dim3(N_QKV / 64, D_MODEL / 64), 256, 0, stream>>>(Wqkv, WqkvT, D_MODEL, N_QKV);
    // 3. qkv = x @ Wqkv + bqkv (bf16), grid 192
    gemm256<1><<<dim3(192, 1, 1), 512, 0, stream>>>(xb, WqkvT, bqkv, qkv, nullptr, nullptr, nullptr, nullptr,
                                                    L_SEQ, N_QKV, D_MODEL, D_MODEL, 8);
    // 4. attention
    attn_kernel<<<dim3(L_SEQ / 64, N_HEADS), 256, 0, stream>>>(qkv, attn_o);
    // 5. Wo^T
    tr_cvt64<<<dim3(D_MODEL / 64, D_MODEL / 64), 256, 0, stream>>>(Wo, WoT, D_MODEL, D_MODEL);
    // 6. proj = attn @ Wo + bo (f32)
    gemm_bt<<<dim3(D_MODEL / 128, L_SEQ / 128), 256, 0, stream>>>(attn_o, WoT, bo, proj, L_SEQ, D_MODEL, D_MODEL);
    // 7. hb = bf16(LN(x + proj))
    ln_kernel<<<L_SEQ, 256, 0, stream>>>(x, proj, g1, be1, hb);
    // 8. W1^T
    tr_cvt64<<<dim3(D_INNER / 64, D_MODEL / 64), 256, 0, stream>>>(W1, W1T, D_MODEL, D_INNER);
    // 9. f1 = gelu(hb @ W1 + b1) (bf16), grid 256
    gemm256<2><<<dim3(256, 1, 1), 512, 0, stream>>>(hb, W1T, b1, f1, nullptr, nullptr, nullptr, nullptr,
                                                    L_SEQ, D_INNER, D_MODEL, D_MODEL, 8);
    // 10. W2^T
    tr_cvt64<<<dim3(D_MODEL / 64, D_INNER / 64), 256, 0, stream>>>(W2, W2T, D_INNER, D_MODEL);
    // 11. f2 partials = f1 @ W2 (split-K=np, f32 planes)
    gemm256<3><<<dim3(64, 1, np), 512, 0, stream>>>(f1, W2T, nullptr, nullptr, part0, part1, part2, part3,
                                                    L_SEQ, D_MODEL, D_INNER, kseg, 8);
    // 12. out = LN(hb + Σparts + b2)*g2+be2
    ln_part_kernel<<<L_SEQ, 256, 0, stream>>>(hb, part0, part1, part2, part3, np, b2, g2, be2, (float*)d_out);
}

// Round 10
// 463.685 us; speedup vs baseline: 4.4456x; 1.0057x over previous
//
#include <hip/hip_runtime.h>
#include <hip/hip_bf16.h>

typedef unsigned short u16;
typedef __attribute__((ext_vector_type(8))) short frag8;   // 8 bf16
typedef __attribute__((ext_vector_type(4))) float facc4;   // 4 f32

#define L_SEQ 2048
#define D_MODEL 2048
#define N_HEADS 16
#define HEAD_D 128
#define N_QKV 6144
#define D_INNER 8192

__device__ __forceinline__ u16 f2b(float f) {
    __hip_bfloat16 h = __float2bfloat16(f);
    return *reinterpret_cast<u16*>(&h);
}

__device__ __forceinline__ float b2f(u16 u) {
    __hip_bfloat16 h = *reinterpret_cast<__hip_bfloat16*>(&u);
    return __bfloat162float(h);
}

__device__ __forceinline__ void gload_lds16(const void* g, void* l) {
    __builtin_amdgcn_global_load_lds(
        (const __attribute__((address_space(1))) unsigned int*)g,
        (__attribute__((address_space(3))) unsigned int*)l, 16, 0, 0);
}

__device__ __forceinline__ float gelu_exact(float x) {
    return 0.5f * x * (1.0f + erff(x * 0.7071067811865475f));
}

// ---------------- elementwise f32 -> bf16 (vectorized) ----------------
__global__ __launch_bounds__(256) void cvt_bf16_kernel(const float* __restrict__ in, u16* __restrict__ out, int n) {
    const int i = (blockIdx.x * 256 + threadIdx.x) * 8;
    if (i >= n) return;
    float4 a = *(const float4*)(in + i);
    float4 b = *(const float4*)(in + i + 4);
    u16 tmp[8];
    tmp[0] = f2b(a.x); tmp[1] = f2b(a.y); tmp[2] = f2b(a.z); tmp[3] = f2b(a.w);
    tmp[4] = f2b(b.x); tmp[5] = f2b(b.y); tmp[6] = f2b(b.z); tmp[7] = f2b(b.w);
    *(uint4*)(out + i) = *(uint4*)tmp;
}

// ---------------- transpose + convert: f32 [R][C] -> bf16 [C][R], 64x64 tiles ----------------
__global__ __launch_bounds__(256) void tr_cvt64(const float* __restrict__ in, u16* __restrict__ out, int R, int C) {
    __shared__ float t[64][68];
    const int bx = blockIdx.x * 64;  // C dim
    const int by = blockIdx.y * 64;  // R dim
    const int tid = threadIdx.x;
    {
        const int r = tid >> 2;
        const int c4 = (tid & 3) * 16;
        const float* src = in + (size_t)(by + r) * C + bx + c4;
#pragma unroll
        for (int j = 0; j < 4; ++j)
            *(float4*)&t[r][c4 + 4 * j] = *(const float4*)(src + 4 * j);
    }
    __syncthreads();
    {
        const int cc = tid >> 2;
        const int rr0 = (tid & 3) * 16;
        u16 tmp[16];
#pragma unroll
        for (int j = 0; j < 16; ++j) tmp[j] = f2b(t[rr0 + j][cc]);
        u16* dst = out + (size_t)(bx + cc) * R + by + rr0;
        *(uint4*)(dst) = *(uint4*)&tmp[0];
        *(uint4*)(dst + 8) = *(uint4*)&tmp[8];
    }
}

// ---------------- legacy 128x128 GEMM (proj) ----------------
__global__ __launch_bounds__(256) void gemm_bt(const u16* __restrict__ A, const u16* __restrict__ Bt,
                                               const float* __restrict__ bias, float* __restrict__ Cout,
                                               int M, int N, int K) {
    __shared__ u16 lA[128 * 64];
    __shared__ u16 lB[128 * 64];
    const int tid = threadIdx.x;
    const int lane = tid & 63, wid = tid >> 6;
    const int wr = wid >> 1, wc = wid & 1;
    const int l15 = lane & 15, g4 = lane >> 4;
    const int bm = blockIdx.y, bn = blockIdx.x;

    const int arow = tid >> 3;
    const int acol = (tid & 7) * 8;
    const size_t abase = (size_t)(bm * 128) * K + acol;
    const size_t bbase = (size_t)(bn * 128) * K + acol;

    facc4 acc[4][4] = {};

    for (int k0 = 0; k0 < K; k0 += 64) {
        if (k0) __syncthreads();
#pragma unroll
        for (int i = 0; i < 4; i++) {
            gload_lds16(A + abase + (size_t)(i * 32 + arow) * K + k0, &lA[i * 2048 + tid * 8]);
            gload_lds16(Bt + bbase + (size_t)(i * 32 + arow) * K + k0, &lB[i * 2048 + tid * 8]);
        }
        __syncthreads();
#pragma unroll
        for (int kk = 0; kk < 64; kk += 32) {
            frag8 af[4], bf[4];
#pragma unroll
            for (int m = 0; m < 4; m++)
                af[m] = *(const frag8*)&lA[(wr * 64 + m * 16 + l15) * 64 + kk + g4 * 8];
#pragma unroll
            for (int n = 0; n < 4; n++)
                bf[n] = *(const frag8*)&lB[(wc * 64 + n * 16 + l15) * 64 + kk + g4 * 8];
#pragma unroll
            for (int m = 0; m < 4; m++)
#pragma unroll
                for (int n = 0; n < 4; n++)
                    acc[m][n] = __builtin_amdgcn_mfma_f32_16x16x32_bf16(af[m], bf[n], acc[m][n], 0, 0, 0);
        }
    }

    const int row0 = bm * 128 + wr * 64 + g4 * 4;
    const int col0 = bn * 128 + wc * 64 + l15;
#pragma unroll
    for (int n = 0; n < 4; n++) {
        const int col = col0 + n * 16;
        const float bv = bias[col];
#pragma unroll
        for (int m = 0; m < 4; m++)
#pragma unroll
            for (int r = 0; r < 4; r++)
                Cout[(size_t)(row0 + m * 16 + r) * N + col] = acc[m][n][r] + bv;
    }
}

// ---------------- gemm256 v10: faithful m201-style 4-phase/BK=64 schedule ----------------
// 256x256 tile, BK=64, 2 LDS dbuf (128 KiB), 8 waves (2M x 4N), per-wave 128x64 output.
// Phase-aligned halves: A-half h = 64-row stripes {r : (r>>6)&1 == h}; B-half h = 32-col
// stripes {c : (c>>5)&1 == h}. Quadrant Q(mh,nh) reads exactly A-half mh + B-half nh
// (uniform across waves). Staging order per tile [A0,B0,B1,A1], one half (2 loads) per phase.
// Counted vmcnt ledger (per-wave, FIFO; induction: entering tile t, {t.B1,t.A1} in flight):
//   p0-end vmcnt(4) retires t.B1 (needed p1); p1-end vmcnt(4) retires t.A1 (needed p2);
//   p3-end vmcnt(4) retires t+1.{A0,B0} (needed next p0). Never drains to 0 mid-loop.
// Swizzle: chunk ^= (rh&7) (2-way in 16-lane groups = free), pre-swizzled global source.
// EPI: 0 f32+bias, 1 bf16+bias, 2 gelu+bf16+bias, 3 f32 partial (plane by blockIdx.z)
template <int EPI>
__global__ __launch_bounds__(512, 2) void gemm256(const u16* __restrict__ A, const u16* __restrict__ Bt,
                                                  const float* __restrict__ bias, void* __restrict__ Cout,
                                                  float* __restrict__ q0, float* __restrict__ q1,
                                                  float* __restrict__ q2, float* __restrict__ q3,
                                                  int M, int N, int K, int kseg, int nbm) {
    __shared__ u16 lds[2 * 32768];  // buf d: A-h0 @ d*32768, A-h1 @ +8192, B-h0 @ +16384, B-h1 @ +24576
    const int tid = threadIdx.x;
    const int lane = tid & 63, wid = tid >> 6;
    const int wm = wid >> 2, wn = wid & 3;
    const int l15 = lane & 15, g4 = lane >> 4;

    // XCD-chunked swizzle, bm-minor (round-8 proven: L2-resident B panels)
    const int nwg = gridDim.x;
    const int q8 = nwg >> 3;
    const int wg = (blockIdx.x & 7) * q8 + (blockIdx.x >> 3);
    const int bm = wg % nbm, bn = wg / nbm;
    const int kb = blockIdx.z * kseg;
    const int ksz = (blockIdx.z == (int)gridDim.z - 1) ? (K - kb) : kseg;
    const int nt = ksz >> 6;  // BK=64 tiles

    // ---- staging addresses (thread covers chunks c0=tid, c1=tid+512 of each half) ----
    const int rr = tid >> 3;                      // 0..63  (row-in-half for c0; c1 = +64)
    const int kk8 = tid & 7;                      // 16B chunk within 128B row
    const int srcE = (kk8 ^ (rr & 7)) << 3;       // pre-swizzled source elem offset
    const u16* aS = A + (size_t)(bm * 256 + rr) * K + kb + srcE;
    const u16* bS = Bt + (size_t)(bn * 256 + ((rr >> 5) << 6) + (rr & 31)) * K + kb + srcE;
    const size_t r128 = (size_t)128 * K;
    const size_t r64 = (size_t)64 * K;
    const size_t c32 = (size_t)32 * K;

    auto stA = [&](int tt, int h) {
        u16* d = &lds[((tt & 1) << 15) + (h << 13)];
        const u16* g = aS + (size_t)tt * 64 + (h ? r64 : 0);
        gload_lds16(g, d + tid * 8);
        gload_lds16(g + r128, d + 4096 + tid * 8);
    };
    auto stB = [&](int tt, int h) {
        u16* d = &lds[((tt & 1) << 15) + 16384 + (h << 13)];
        const u16* g = bS + (size_t)tt * 64 + (h ? c32 : 0);
        gload_lds16(g, d + tid * 8);
        gload_lds16(g + r128, d + 4096 + tid * 8);
    };

    // ---- fragment read offsets (u16 units) ----
    const int ch0 = (g4 ^ (l15 & 7)) << 3;  // chunk*8 for kh=0
    const int ch1 = ch0 ^ 32;               // kh=1 (chunk ^ 4)
    const int aRdBase = (wm * 64 + l15) * 64;
    const int bRdBase = (wn * 32 + l15) * 64;

    frag8 a[4][2], b0[2][2], b1[2][2];
    facc4 acc[8][4] = {};

    auto rdA = [&](int bufo, int mh) {
#pragma unroll
        for (int mi = 0; mi < 4; ++mi) {
            const int base = bufo + mh * 8192 + aRdBase + mi * 1024;
            a[mi][0] = *(const frag8*)&lds[base + ch0];
            a[mi][1] = *(const frag8*)&lds[base + ch1];
        }
    };
    auto rdB = [&](int bufo, int nh, frag8(&bb)[2][2]) {
#pragma unroll
        for (int ni = 0; ni < 2; ++ni) {
            const int base = bufo + 16384 + nh * 8192 + bRdBase + ni * 1024;
            bb[ni][0] = *(const frag8*)&lds[base + ch0];
            bb[ni][1] = *(const frag8*)&lds[base + ch1];
        }
    };
    auto quad = [&](int mh, int nh, frag8(&bb)[2][2]) {
        __builtin_amdgcn_s_setprio(1);
#pragma unroll
        for (int kh = 0; kh < 2; ++kh)
#pragma unroll
            for (int mi = 0; mi < 4; ++mi)
#pragma unroll
                for (int ni = 0; ni < 2; ++ni)
                    acc[mh * 4 + mi][nh * 2 + ni] =
                        __builtin_amdgcn_mfma_f32_16x16x32_bf16(a[mi][kh], bb[ni][kh],
                                                                acc[mh * 4 + mi][nh * 2 + ni], 0, 0, 0);
        __builtin_amdgcn_s_setprio(0);
    };

#define SB __builtin_amdgcn_sched_barrier(0)
#define BAR __builtin_amdgcn_s_barrier()

    // ---- prologue: stage tile 0 [A0,B0,B1,A1]; retire A0,B0; keep B1,A1 in flight ----
    stA(0, 0); stB(0, 0); stB(0, 1); stA(0, 1);
    asm volatile("s_waitcnt vmcnt(4)" ::: "memory");
    BAR; SB;

    for (int t = 0; t < nt; ++t) {
        const int bufo = (t & 1) << 15;
        const bool so = (t + 1 < nt);
        // ---- phase 0: Q(0,0) ----
        rdA(bufo, 0);
        rdB(bufo, 0, b0);
        if (so) stA(t + 1, 0);
        SB; BAR; SB;
        quad(0, 0, b0);
        if (so) asm volatile("s_waitcnt vmcnt(4)" ::: "memory");
        else    asm volatile("s_waitcnt vmcnt(2)" ::: "memory");
        BAR; SB;
        // ---- phase 1: Q(0,1) ----
        rdB(bufo, 1, b1);
        if (so) stB(t + 1, 0);
        SB; BAR; SB;
        quad(0, 1, b1);
        if (so) asm volatile("s_waitcnt vmcnt(4)" ::: "memory");
        else    asm volatile("s_waitcnt vmcnt(0)" ::: "memory");
        BAR; SB;
        // ---- phase 2: Q(1,0) ----
        rdA(bufo, 1);
        if (so) stB(t + 1, 1);
        SB; BAR; SB;
        quad(1, 0, b0);
        BAR; SB;
        // ---- phase 3: Q(1,1) ----
        if (so) stA(t + 1, 1);
        SB; BAR; SB;
        quad(1, 1, b1);
        if (so) asm volatile("s_waitcnt vmcnt(4)" ::: "memory");
        BAR; SB;
    }
#undef SB
#undef BAR

    // ---- epilogue ----
    const int row0 = bm * 256 + wm * 128 + g4 * 4;
    const int col0 = bn * 256 + wn * 64 + l15;
    float* fout;
    if (EPI == 3) {
        const int z = blockIdx.z;
        fout = (z == 0) ? q0 : (z == 1) ? q1 : (z == 2) ? q2 : q3;
    } else {
        fout = (float*)Cout;
    }
#pragma unroll
    for (int nf = 0; nf < 4; nf++) {
        const int col = col0 + nf * 16;
        const float bv = (EPI == 3) ? 0.0f : bias[col];
#pragma unroll
        for (int mf = 0; mf < 8; mf++) {
#pragma unroll
            for (int r = 0; r < 4; r++) {
                const int row = row0 + mf * 16 + r;
                float v = acc[mf][nf][r] + bv;
                if (EPI == 2) v = gelu_exact(v);
                if (EPI == 0 || EPI == 3)
                    fout[(size_t)row * N + col] = v;
                else
                    ((u16*)Cout)[(size_t)row * N + col] = f2b(v);
            }
        }
    }
}

// ---------------- flash attention v7 (unchanged, passing since round 7) ----------------
__global__ __launch_bounds__(256) void attn_kernel(const u16* __restrict__ qkv, u16* __restrict__ out) {
    __shared__ u16 kT[64 * 128];
    __shared__ u16 vT[128 * 64];
    const int h = blockIdx.y;
    const int qb = (blockIdx.y < 8) ? ((int)gridDim.x - 1 - (int)blockIdx.x) : (int)blockIdx.x;
    const int tid = threadIdx.x;
    const int lane = tid & 63, w = tid >> 6;
    const int l15 = lane & 15, g4 = lane >> 4;
    const int q0 = qb * 64 + w * 16;
    const float scale = 0.022097086912079608f;

    frag8 qf[4];
    {
        const u16* qrow = qkv + (size_t)(q0 + l15) * N_QKV + h * HEAD_D + g4 * 8;
#pragma unroll
        for (int c = 0; c < 4; c++) qf[c] = *(const frag8*)(qrow + c * 32);
    }

    float m_run = -1e30f, l_run = 0.0f;
    facc4 o[8] = {};

    const int src0 = ((g4 & 1) << 5) + l15;
    const int src1 = src0 + 16;
    const bool hi = (g4 & 2) != 0;

    const int nt = qb + 1;
    for (int t = 0; t < nt; ++t) {
        const int kbase = t * 64;
        if (t) __syncthreads();
        const u16* kg_ptr = qkv + (size_t)kbase * N_QKV + D_MODEL + h * HEAD_D;
        const u16* vg_ptr = kg_ptr + D_MODEL;
        uint4 vv[4];
#pragma unroll
        for (int i = 0; i < 4; ++i)
            vv[i] = *(const uint4*)(vg_ptr + (size_t)lane * N_QKV + w * 32 + i * 8);
#pragma unroll
        for (int p = 0; p < 4; ++p) {
            const int c = p * 256 + tid;
            const int row = c >> 4;
            const int colb = (c & 15) << 4;
            const int srcb = colb ^ ((row & 7) << 4);
            gload_lds16(kg_ptr + (size_t)row * N_QKV + (srcb >> 1), &kT[c * 8]);
        }
#pragma unroll
        for (int i = 0; i < 4; ++i) {
            const u16* pv = (const u16*)&vv[i];
#pragma unroll
            for (int e = 0; e < 8; ++e) {
                const int d = w * 32 + i * 8 + e;
                vT[d * 64 + ((((lane >> 3) ^ (d & 7)) << 3) | (lane & 7))] = pv[e];
            }
        }
        __syncthreads();

        const bool last = (t == nt - 1);

        float st[16];
        float mx = -1e30f;
#pragma unroll
        for (int ks = 0; ks < 4; ++ks) {
            const bool active = !last || (ks <= w);
            if (active) {
                facc4 s = {};
                const int kl = ks * 16 + l15;
#pragma unroll
                for (int c = 0; c < 4; ++c) {
                    const int colb = (g4 * 16 + c * 64) ^ ((kl & 7) << 4);
                    frag8 kf = *(const frag8*)&kT[kl * 128 + (colb >> 1)];
                    s = __builtin_amdgcn_mfma_f32_16x16x32_bf16(kf, qf[c], s, 0, 0, 0);
                }
#pragma unroll
                for (int r = 0; r < 4; ++r) {
                    float v = s[r] * scale;
                    if (last) {
                        const int key = kbase + ks * 16 + g4 * 4 + r;
                        if (key > q0 + l15) v = -1e30f;
                    }
                    st[ks * 4 + r] = v;
                    mx = fmaxf(mx, v);
                }
            } else {
#pragma unroll
                for (int r = 0; r < 4; ++r) st[ks * 4 + r] = -1e30f;
            }
        }

        mx = fmaxf(mx, __shfl_xor(mx, 16));
        mx = fmaxf(mx, __shfl_xor(mx, 32));
        const bool skip = __all(mx <= m_run + 8.0f);
        const float m_new = skip ? m_run : fmaxf(m_run, mx);
        const float alpha = __expf(m_run - m_new);
        float ps = 0.0f;
        uint2 pb[4];
#pragma unroll
        for (int ks = 0; ks < 4; ++ks) {
            const float p0 = __expf(st[ks * 4 + 0] - m_new);
            const float p1 = __expf(st[ks * 4 + 1] - m_new);
            const float p2 = __expf(st[ks * 4 + 2] - m_new);
            const float p3 = __expf(st[ks * 4 + 3] - m_new);
            ps += (p0 + p1) + (p2 + p3);
            pb[ks].x = (unsigned)f2b(p0) | ((unsigned)f2b(p1) << 16);
            pb[ks].y = (unsigned)f2b(p2) | ((unsigned)f2b(p3) << 16);
        }
        ps += __shfl_xor(ps, 16);
        ps += __shfl_xor(ps, 32);
        l_run = l_run * alpha + ps;
        m_run = m_new;
        if (!skip) {
#pragma unroll
            for (int c8 = 0; c8 < 8; ++c8)
#pragma unroll
                for (int r = 0; r < 4; ++r) o[c8][r] *= alpha;
        }

#pragma unroll
        for (int kp = 0; kp < 2; ++kp) {
            const bool kp_active = !last || (kp == 0) || (w >= 2);
            if (kp_active) {
                const uint2 a = pb[2 * kp], b = pb[2 * kp + 1];
                const unsigned a0 = __shfl(a.x, src0), a1 = __shfl(a.y, src0);
                const unsigned a2 = __shfl(a.x, src1), a3 = __shfl(a.y, src1);
                const unsigned b0 = __shfl(b.x, src0), b1 = __shfl(b.y, src0);
                const unsigned b2 = __shfl(b.x, src1), b3 = __shfl(b.y, src1);
                union { unsigned u[4]; frag8 f; } pu;
                pu.u[0] = hi ? b0 : a0;
                pu.u[1] = hi ? b1 : a1;
                pu.u[2] = hi ? b2 : a2;
                pu.u[3] = hi ? b3 : a3;
                const frag8 pf = pu.f;
#pragma unroll
                for (int c8 = 0; c8 < 8; ++c8) {
                    const int d = c8 * 16 + l15;
                    const int ch = (((kp * 4 + g4) ^ (l15 & 7)) << 3);
                    frag8 vf = *(const frag8*)&vT[d * 64 + ch];
                    o[c8] = __builtin_amdgcn_mfma_f32_16x16x32_bf16(vf, pf, o[c8], 0, 0, 0);
                }
            }
        }
    }

    const float inv_l = 1.0f / l_run;
    u16* orow = out + (size_t)(q0 + l15) * D_MODEL + h * HEAD_D;
#pragma unroll
    for (int c8 = 0; c8 < 8; ++c8) {
        uint2 st2;
        st2.x = (unsigned)f2b(o[c8][0] * inv_l) | ((unsigned)f2b(o[c8][1] * inv_l) << 16);
        st2.y = (unsigned)f2b(o[c8][2] * inv_l) | ((unsigned)f2b(o[c8][3] * inv_l) << 16);
        *(uint2*)&orow[c8 * 16 + g4 * 4] = st2;
    }
}

// ---------------- residual + layernorm -> bf16 ----------------
__global__ __launch_bounds__(256) void ln_kernel(const float* __restrict__ a, const float* __restrict__ b,
                                                 const float* __restrict__ gamma, const float* __restrict__ beta,
                                                 u16* __restrict__ outb) {
    __shared__ float red[8];
    const int row = blockIdx.x;
    const int tid = threadIdx.x;
    const float* pa = a + (size_t)row * D_MODEL;
    const float* pb = b + (size_t)row * D_MODEL;
    float v[8];
    float s = 0.0f, s2 = 0.0f;
#pragma unroll
    for (int i = 0; i < 8; i++) {
        const int c = tid + i * 256;
        const float x = pa[c] + pb[c];
        v[i] = x;
        s += x;
        s2 += x * x;
    }
#pragma unroll
    for (int off = 32; off; off >>= 1) {
        s += __shfl_xor(s, off);
        s2 += __shfl_xor(s2, off);
    }
    if ((tid & 63) == 0) { red[(tid >> 6) * 2] = s; red[(tid >> 6) * 2 + 1] = s2; }
    __syncthreads();
    s = red[0] + red[2] + red[4] + red[6];
    s2 = red[1] + red[3] + red[5] + red[7];
    const float mean = s * (1.0f / D_MODEL);
    const float var = s2 * (1.0f / D_MODEL) - mean * mean;
    const float rstd = rsqrtf(var + 1e-5f);
#pragma unroll
    for (int i = 0; i < 8; i++) {
        const int c = tid + i * 256;
        outb[(size_t)row * D_MODEL + c] = f2b((v[i] - mean) * rstd * gamma[c] + beta[c]);
    }
}

// ---------------- bf16 residual + Σ split-K partials + bias + layernorm -> f32 ----------------
__global__ __launch_bounds__(256) void ln_part_kernel(const u16* __restrict__ hb,
                                                      const float* __restrict__ p0, const float* __restrict__ p1,
                                                      const float* __restrict__ p2, const float* __restrict__ p3,
                                                      int np, const float* __restrict__ bias,
                                                      const float* __restrict__ gamma, const float* __restrict__ beta,
                                                      float* __restrict__ outf) {
    __shared__ float red[8];
    const int row = blockIdx.x;
    const int tid = threadIdx.x;
    const size_t rb = (size_t)row * D_MODEL;
    float v[8];
    float s = 0.0f, s2 = 0.0f;
#pragma unroll
    for (int i = 0; i < 8; i++) {
        const int c = tid + i * 256;
        float x = b2f(hb[rb + c]) + bias[c] + p0[rb + c] + p1[rb + c];
        if (np > 2) x += p2[rb + c];
        if (np > 3) x += p3[rb + c];
        v[i] = x;
        s += x;
        s2 += x * x;
    }
#pragma unroll
    for (int off = 32; off; off >>= 1) {
        s += __shfl_xor(s, off);
        s2 += __shfl_xor(s2, off);
    }
    if ((tid & 63) == 0) { red[(tid >> 6) * 2] = s; red[(tid >> 6) * 2 + 1] = s2; }
    __syncthreads();
    s = red[0] + red[2] + red[4] + red[6];
    s2 = red[1] + red[3] + red[5] + red[7];
    const float mean = s * (1.0f / D_MODEL);
    const float var = s2 * (1.0f / D_MODEL) - mean * mean;
    const float rstd = rsqrtf(var + 1e-5f);
#pragma unroll
    for (int i = 0; i < 8; i++) {
        const int c = tid + i * 256;
        outf[rb + c] = (v[i] - mean) * rstd * gamma[c] + beta[c];
    }
}

extern "C" void kernel_launch(void* const* d_in, const int* in_sizes, int n_in,
                              void* d_out, int out_size, void* d_ws, size_t ws_size,
                              hipStream_t stream) {
    const float* x    = (const float*)d_in[0];
    const float* Wqkv = (const float*)d_in[1];
    const float* bqkv = (const float*)d_in[2];
    const float* Wo   = (const float*)d_in[3];
    const float* bo   = (const float*)d_in[4];
    const float* W1   = (const float*)d_in[5];
    const float* b1   = (const float*)d_in[6];
    const float* W2   = (const float*)d_in[7];
    const float* b2   = (const float*)d_in[8];
    const float* g1   = (const float*)d_in[9];
    const float* be1  = (const float*)d_in[10];
    const float* g2   = (const float*)d_in[11];
    const float* be2  = (const float*)d_in[12];

    char* ws = (char*)d_ws;
    const size_t MB = 1024 * 1024;
    u16*  xb     = (u16*)(ws + 0);          // [0,8)
    u16*  WqkvT  = (u16*)(ws + 8 * MB);     // [8,32)
    u16*  qkv    = (u16*)(ws + 32 * MB);    // [32,56)
    u16*  attn_o = (u16*)(ws + 56 * MB);    // [56,64)
    u16*  WoT    = (u16*)(ws + 8 * MB);     // [8,16)   reuses WqkvT (dead)
    float* proj  = (float*)(ws + 16 * MB);  // [16,32)
    u16*  hb     = (u16*)(ws + 0);          // [0,8)    reuses xb (dead)
    u16*  W1T    = (u16*)(ws + 8 * MB);     // [8,40)   reuses WoT+proj (dead)
    u16*  f1     = (u16*)(ws + 40 * MB);    // [40,72)
    u16*  W2T    = (u16*)(ws + 72 * MB);    // [72,104)
    float* part0 = (float*)(ws + 8 * MB);   // [8,24)   reuses W1T (dead)
    float* part1 = (float*)(ws + 24 * MB);  // [24,40)
    float* part2 = (float*)(ws + 104 * MB); // [104,120)
    float* part3 = (float*)(ws + 120 * MB); // [120,136) only if ws >= 136 MB

    const int np = (ws_size >= 136 * MB) ? 4 : 3;
    const int kseg = (np == 4) ? 2048 : 2688;  // multiples of 64; last plane takes remainder

    // 1. x -> bf16
    cvt_bf16_kernel<<<2048, 256, 0, stream>>>(x, xb, L_SEQ * D_MODEL);
    // 2. Wqkv^T
    tr_cvt64<<<dim3(N_QKV / 64, D_MODEL / 64), 256, 0, stream>>>(Wqkv, WqkvT, D_MODEL, N_QKV);
    // 3. qkv = x @ Wqkv + bqkv (bf16), grid 192
    gemm256<1><<<dim3(192, 1, 1), 512, 0, stream>>>(xb, WqkvT, bqkv, qkv, nullptr, nullptr, nullptr, nullptr,
                                                    L_SEQ, N_QKV, D_MODEL, D_MODEL, 8);
    // 4. attention
    attn_kernel<<<dim3(L_SEQ / 64, N_HEADS), 256, 0, stream>>>(qkv, attn_o);
    // 5. Wo^T
    tr_cvt64<<<dim3(D_MODEL / 64, D_MODEL / 64), 256, 0, stream>>>(Wo, WoT, D_MODEL, D_MODEL);
    // 6. proj = attn @ Wo + bo (f32)
    gemm_bt<<<dim3(D_MODEL / 128, L_SEQ / 128), 256, 0, stream>>>(attn_o, WoT, bo, proj, L_SEQ, D_MODEL, D_MODEL);
    // 7. hb = bf16(LN(x + proj))
    ln_kernel<<<L_SEQ, 256, 0, stream>>>(x, proj, g1, be1, hb);
    // 8. W1^T
    tr_cvt64<<<dim3(D_INNER / 64, D_MODEL / 64), 256, 0, stream>>>(W1, W1T, D_MODEL, D_INNER);
    // 9. f1 = gelu(hb @ W1 + b1) (bf16), grid 256
    gemm256<2><<<dim3(256, 1, 1), 512, 0, stream>>>(hb, W1T, b1, f1, nullptr, nullptr, nullptr, nullptr,
                                                    L_SEQ, D_INNER, D_MODEL, D_MODEL, 8);
    // 10. W2^T
    tr_cvt64<<<dim3(D_MODEL / 64, D_INNER / 64), 256, 0, stream>>>(W2, W2T, D_INNER, D_MODEL);
    // 11. f2 partials = f1 @ W2 (split-K=np, f32 planes)
    gemm256<3><<<dim3(64, 1, np), 512, 0, stream>>>(f1, W2T, nullptr, nullptr, part0, part1, part2, part3,
                                                    L_SEQ, D_MODEL, D_INNER, kseg, 8);
    // 12. out = LN(hb + Σparts + b2)*g2+be2
    ln_part_kernel<<<L_SEQ, 256, 0, stream>>>(hb, part0, part1, part2, part3, np, b2, g2, be2, (float*)d_out);
}